// Round 2
// baseline (7987.489 us; speedup 1.0000x reference)
//
#include <hip/hip_runtime.h>

// STA-LSTM forward, fp32 baseline (lean-ws revision).
// B=4096 S=16 D=256 HS=HT=512. Output: y (B,1) fp32.
//
// Round-1 crash theory: ws overflow (needed 377.5 MB). This revision needs
// 204.0 MB of d_ws and keeps all static LDS < 64 KB/block.
//   - no zbuf: t==0 uses NSEG=1 gemm variants + ZC-templated lstm pointwise
//   - c / lh / lc: single buffers, updated in place (same-index or
//     cross-kernel sequential access only)
//   - xt aliases av (softmax is elementwise-in-place per thread)
//   - h_ctx: one 8 MB slot recomputed per ta step (re-reads H3 per step)

constexpr int Bb = 4096;
constexpr int Ss = 16;
constexpr int Dd = 256;
constexpr int Hh = 512;   // HS == HT

struct Seg { const float* A; const float* Bm; int lda; int ldb; int K; };

__device__ __forceinline__ float sigm(float x) { return 1.0f / (1.0f + expf(-x)); }

// ---------------- generic multi-segment fp32 GEMM ----------------
// C[M,N] = sum_seg A_seg @ B_seg ; EPI==1: tanh(acc + bias[n])
template<int BM, int BN, int TM, int TN, int NSEG, int EPI>
__global__ __launch_bounds__(256) void gemm_k(Seg s0, Seg s1, Seg s2,
                                              const float* __restrict__ bias,
                                              float* __restrict__ C, int ldc)
{
    __shared__ float As[16][BM + 4];
    __shared__ float Bs[16][BN + 4];
    const int tid  = threadIdx.x;
    const int row0 = blockIdx.x * BM;
    const int col0 = blockIdx.y * BN;
    constexpr int NTX = BN / TN;
    const int tx = tid % NTX;
    const int ty = tid / NTX;

    float acc[TM][TN];
#pragma unroll
    for (int i = 0; i < TM; i++)
#pragma unroll
        for (int j = 0; j < TN; j++) acc[i][j] = 0.0f;

#pragma unroll
    for (int sgi = 0; sgi < NSEG; ++sgi) {
        Seg sg = (sgi == 0) ? s0 : ((sgi == 1) ? s1 : s2);
        const int nkt = sg.K / 16;
        for (int kt = 0; kt < nkt; ++kt) {
            const int k0 = kt * 16;
            constexpr int ACNT = (BM * 4) / 256;
#pragma unroll
            for (int i = 0; i < ACNT; i++) {
                int idx = tid + i * 256;
                int r = idx >> 2, kq = idx & 3;
                const float4 v = *reinterpret_cast<const float4*>(
                    sg.A + (size_t)(row0 + r) * sg.lda + k0 + kq * 4);
                As[kq * 4 + 0][r] = v.x;
                As[kq * 4 + 1][r] = v.y;
                As[kq * 4 + 2][r] = v.z;
                As[kq * 4 + 3][r] = v.w;
            }
            constexpr int BCNT = (BN * 4) / 256;
#pragma unroll
            for (int i = 0; i < BCNT; i++) {
                int idx = tid + i * 256;
                int k = idx / (BN / 4), nq = idx % (BN / 4);
                const float4 v = *reinterpret_cast<const float4*>(
                    sg.Bm + (size_t)(k0 + k) * sg.ldb + col0 + nq * 4);
                *reinterpret_cast<float4*>(&Bs[k][nq * 4]) = v;
            }
            __syncthreads();
#pragma unroll
            for (int k = 0; k < 16; k++) {
                float a_[TM], b_[TN];
#pragma unroll
                for (int i = 0; i < TM; i++) a_[i] = As[k][ty * TM + i];
#pragma unroll
                for (int j = 0; j < TN; j++) b_[j] = Bs[k][tx * TN + j];
#pragma unroll
                for (int i = 0; i < TM; i++)
#pragma unroll
                    for (int j = 0; j < TN; j++)
                        acc[i][j] = fmaf(a_[i], b_[j], acc[i][j]);
            }
            __syncthreads();
        }
    }

#pragma unroll
    for (int i = 0; i < TM; i++) {
        int r = row0 + ty * TM + i;
#pragma unroll
        for (int j = 0; j < TN; j++) {
            int cc = col0 + tx * TN + j;
            float v = acc[i][j];
            if (EPI == 1) v = tanhf(v + bias[cc]);
            C[(size_t)r * ldc + cc] = v;
        }
    }
}

// ---------------- init: y0 = X[:,0,255] ----------------
__global__ __launch_bounds__(256) void init_k(const float* __restrict__ X,
                                              float* __restrict__ yv)
{
    int idx = blockIdx.x * 256 + threadIdx.x;
    if (idx < Bb) yv[idx] = X[(size_t)idx * Ss * Dd + (Dd - 1)];
}

// ---------------- softmax over D + scale by x_t (in-place a -> xt ok) ----------------
__global__ __launch_bounds__(256) void softmax_xt_k(const float* __restrict__ a,
                                                    const float* __restrict__ X,
                                                    float* __restrict__ xt, int t)
{
    int b = blockIdx.x, tid = threadIdx.x;
    __shared__ float red[256];
    float v = a[(size_t)b * Dd + tid];
    red[tid] = v; __syncthreads();
    for (int s = 128; s > 0; s >>= 1) {
        if (tid < s) red[tid] = fmaxf(red[tid], red[tid + s]);
        __syncthreads();
    }
    float mx = red[0]; __syncthreads();
    float e = expf(v - mx);
    red[tid] = e; __syncthreads();
    for (int s = 128; s > 0; s >>= 1) {
        if (tid < s) red[tid] += red[tid + s];
        __syncthreads();
    }
    float inv = 1.0f / red[0];
    xt[(size_t)b * Dd + tid] = e * inv * X[(size_t)b * Ss * Dd + (size_t)t * Dd + tid];
}

// ---------------- sa LSTM pointwise (c in-place; ZC: c_prev==0) ----------------
template<int ZC>
__global__ __launch_bounds__(256) void lstm_sa_k(const float* __restrict__ gates,
                                                 const float* __restrict__ bias,
                                                 float* __restrict__ c_io,
                                                 float* __restrict__ h_out)
{
    int idx = blockIdx.x * 256 + threadIdx.x;   // over Bb*Hh
    int b = idx >> 9, j = idx & 511;
    const float* g = gates + (size_t)b * 4 * Hh;
    float gi = g[j]          + bias[j];
    float gf = g[Hh + j]     + bias[Hh + j];
    float gg = g[2 * Hh + j] + bias[2 * Hh + j];
    float go = g[3 * Hh + j] + bias[3 * Hh + j];
    float i_ = sigm(gi), f_ = sigm(gf), gv = tanhf(gg), o_ = sigm(go);
    float cp = ZC ? 0.0f : c_io[idx];
    float c = f_ * cp + i_ * gv;
    c_io[idx] = c;
    h_out[idx] = o_ * tanhf(c);
}

// ---------------- ta LSTM pointwise (+ rank-1 y_prev*ta_Wy; lc in-place) ----------------
template<int ZC>
__global__ __launch_bounds__(256) void lstm_ta_k(const float* __restrict__ gates,
                                                 const float* __restrict__ bias,
                                                 const float* __restrict__ wy,
                                                 const float* __restrict__ yv,
                                                 float* __restrict__ c_io,
                                                 float* __restrict__ h_out)
{
    int idx = blockIdx.x * 256 + threadIdx.x;
    int b = idx >> 9, j = idx & 511;
    const float* g = gates + (size_t)b * 4 * Hh;
    float yb = yv[b];
    float gi = g[j]          + bias[j]          + yb * wy[j];
    float gf = g[Hh + j]     + bias[Hh + j]     + yb * wy[Hh + j];
    float gg = g[2 * Hh + j] + bias[2 * Hh + j] + yb * wy[2 * Hh + j];
    float go = g[3 * Hh + j] + bias[3 * Hh + j] + yb * wy[3 * Hh + j];
    float i_ = sigm(gi), f_ = sigm(gf), gv = tanhf(gg), o_ = sigm(go);
    float cp = ZC ? 0.0f : c_io[idx];
    float c = f_ * cp + i_ * gv;
    c_io[idx] = c;
    h_out[idx] = o_ * tanhf(c);
}

// ---------------- beta = softmax(tanh(h_t @ ta_Wa + ta_ba) @ ta_Va) ----------------
// s0 == 0 in the reference, so the ta_Ua term vanishes; all (b,t) at once.
// LDS: 32 KB (Wa) + ~3.3 KB. H3 rows read from global (16-lane broadcast, L1).
__global__ __launch_bounds__(256) void beta_k(const float* __restrict__ H3,
                                              const float* __restrict__ taWa,
                                              const float* __restrict__ taba,
                                              const float* __restrict__ taVa,
                                              float* __restrict__ beta)
{
    int bx = blockIdx.x, t = blockIdx.y, tid = threadIdx.x;
    __shared__ float Was[512 * 16];
    __shared__ float Vas[256];
    __shared__ float tt[16][17];
    __shared__ float lt[16][17];
    for (int i = tid; i < 512 * 16; i += 256) Was[i] = taWa[i];
    Vas[tid] = taVa[tid];
    __syncthreads();
    int r = tid >> 4, n = tid & 15;
    int b = bx * 16 + r;
    const float* hrow = H3 + ((size_t)t * Bb + b) * Hh;
    float acc = taba[n];
    for (int k = 0; k < 512; k++) acc = fmaf(hrow[k], Was[k * 16 + n], acc);
    tt[r][n] = tanhf(acc);
    __syncthreads();
    float l = 0.0f;
#pragma unroll
    for (int m = 0; m < 16; m++) l = fmaf(tt[r][m], Vas[m * 16 + n], l);
    lt[r][n] = l;
    __syncthreads();
    float mx = -1e30f;
#pragma unroll
    for (int m = 0; m < 16; m++) mx = fmaxf(mx, lt[r][m]);
    float sum = 0.0f;
#pragma unroll
    for (int m = 0; m < 16; m++) sum += expf(lt[r][m] - mx);
    beta[((size_t)t * Bb + b) * 16 + n] = expf(l - mx) / sum;
}

// ---------------- h_ctx for ONE t: HC[b][:] = sum_s beta[t][b][s] * H3[s][b][:] ----------------
__global__ __launch_bounds__(256) void hctx_t_k(const float* __restrict__ H3,
                                                const float* __restrict__ beta,
                                                float* __restrict__ HCt, int t)
{
    int b = blockIdx.x, tid = threadIdx.x;
    __shared__ float Hs[16][513];
    __shared__ float bs[16];
    for (int i = tid; i < 16 * 512; i += 256) {
        int s = i >> 9, h = i & 511;
        Hs[s][h] = H3[((size_t)s * Bb + b) * Hh + h];
    }
    if (tid < 16) bs[tid] = beta[((size_t)t * Bb + b) * 16 + tid];
    __syncthreads();
    for (int h = tid; h < Hh; h += 256) {
        float acc = 0.0f;
#pragma unroll
        for (int s = 0; s < 16; s++) acc = fmaf(bs[s], Hs[s][h], acc);
        HCt[(size_t)b * Hh + h] = acc;
    }
}

// ---------------- y = lh @ fc_W.T + fc_b ----------------
__global__ __launch_bounds__(256) void y_k(const float* __restrict__ lh,
                                           const float* __restrict__ fcW,
                                           const float* __restrict__ fcb,
                                           float* __restrict__ yv,
                                           float* __restrict__ outp)
{
    int b = blockIdx.x, tid = threadIdx.x;
    __shared__ float red[256];
    float p = lh[(size_t)b * Hh + tid] * fcW[tid]
            + lh[(size_t)b * Hh + 256 + tid] * fcW[256 + tid];
    red[tid] = p; __syncthreads();
    for (int s = 128; s > 0; s >>= 1) {
        if (tid < s) red[tid] += red[tid + s];
        __syncthreads();
    }
    if (tid == 0) {
        float y = red[0] + fcb[0];
        yv[b] = y;
        if (outp) outp[b] = y;
    }
}

extern "C" void kernel_launch(void* const* d_in, const int* in_sizes, int n_in,
                              void* d_out, int out_size, void* d_ws, size_t ws_size,
                              hipStream_t stream)
{
    (void)in_sizes; (void)n_in; (void)out_size; (void)ws_size;
    const float* X     = (const float*)d_in[0];
    const float* sa_W  = (const float*)d_in[1];
    const float* sa_U  = (const float*)d_in[2];
    const float* sa_b  = (const float*)d_in[3];
    const float* sa_Wa = (const float*)d_in[4];
    const float* sa_Ua = (const float*)d_in[5];
    const float* sa_ba = (const float*)d_in[6];
    const float* sa_Va = (const float*)d_in[7];
    const float* ta_Wa = (const float*)d_in[8];
    // d_in[9] = ta_Ua : multiplied by s0 == 0 in the reference -> unused
    const float* ta_ba = (const float*)d_in[10];
    const float* ta_Va = (const float*)d_in[11];
    const float* ta_W  = (const float*)d_in[12];
    const float* ta_U  = (const float*)d_in[13];
    const float* ta_b  = (const float*)d_in[14];
    const float* ta_Wy = (const float*)d_in[15];
    const float* fc_W  = (const float*)d_in[16];
    const float* fc_b  = (const float*)d_in[17];

    float* ws = (float*)d_ws;
    size_t off = 0;
    auto alloc = [&](size_t n) { float* p = ws + off; off += n; return p; };
    float* tmp   = alloc((size_t)Bb * Dd);        //  4 MB
    float* avxt  = alloc((size_t)Bb * Dd);        //  4 MB (av, then xt in-place)
    float* gates = alloc((size_t)Bb * 4 * Hh);    // 32 MB
    float* H3    = alloc((size_t)Ss * Bb * Hh);   // 128 MB
    float* beta  = alloc((size_t)Ss * Bb * Ss);   //  4 MB
    float* cbuf  = alloc((size_t)Bb * Hh);        //  8 MB (in-place)
    float* lh    = alloc((size_t)Bb * Hh);        //  8 MB
    float* lc    = alloc((size_t)Bb * Hh);        //  8 MB
    float* hct   = alloc((size_t)Bb * Hh);        //  8 MB (per-step h_ctx)
    float* yv    = alloc((size_t)Bb);             // 16 KB
    // total: 204.0 MB

    init_k<<<dim3(16), 256, 0, stream>>>(X, yv);

    // ---- spatial-attention LSTM ----
    for (int t = 0; t < Ss; ++t) {
        const float* h_prev = (t == 0) ? nullptr : (H3 + (size_t)(t - 1) * Bb * Hh);

        // tmp = tanh(x_t @ sa_Wa + h @ Ua[:HS] + c @ Ua[HS:] + sa_ba)
        Seg s0{ X + (size_t)t * Dd, sa_Wa, Ss * Dd, Dd, Dd };
        if (t == 0) {
            gemm_k<64, 64, 4, 4, 1, 1><<<dim3(Bb / 64, Dd / 64), 256, 0, stream>>>(
                s0, s0, s0, sa_ba, tmp, Dd);
        } else {
            Seg s1{ h_prev, sa_Ua, Hh, Dd, Hh };
            Seg s2{ cbuf, sa_Ua + (size_t)Hh * Dd, Hh, Dd, Hh };
            gemm_k<64, 64, 4, 4, 3, 1><<<dim3(Bb / 64, Dd / 64), 256, 0, stream>>>(
                s0, s1, s2, sa_ba, tmp, Dd);
        }

        // av = tmp @ sa_Va
        Seg v0{ tmp, sa_Va, Dd, Dd, Dd };
        gemm_k<64, 64, 4, 4, 1, 0><<<dim3(Bb / 64, Dd / 64), 256, 0, stream>>>(
            v0, v0, v0, nullptr, avxt, Dd);

        softmax_xt_k<<<Bb, 256, 0, stream>>>(avxt, X, avxt, t);

        // gates = xt @ sa_W (+ h @ sa_U)
        Seg g0{ avxt, sa_W, Dd, 4 * Hh, Dd };
        if (t == 0) {
            gemm_k<128, 128, 8, 8, 1, 0><<<dim3(Bb / 128, (4 * Hh) / 128), 256, 0, stream>>>(
                g0, g0, g0, nullptr, gates, 4 * Hh);
            lstm_sa_k<1><<<(Bb * Hh) / 256, 256, 0, stream>>>(
                gates, sa_b, cbuf, H3 + (size_t)t * Bb * Hh);
        } else {
            Seg g1{ h_prev, sa_U, Hh, 4 * Hh, Hh };
            gemm_k<128, 128, 8, 8, 2, 0><<<dim3(Bb / 128, (4 * Hh) / 128), 256, 0, stream>>>(
                g0, g1, g1, nullptr, gates, 4 * Hh);
            lstm_sa_k<0><<<(Bb * Hh) / 256, 256, 0, stream>>>(
                gates, sa_b, cbuf, H3 + (size_t)t * Bb * Hh);
        }
    }

    // ---- temporal attention weights (all steps; s0 == 0) ----
    beta_k<<<dim3(Bb / 16, Ss), 256, 0, stream>>>(H3, ta_Wa, ta_ba, ta_Va, beta);

    // ---- temporal LSTM ----
    for (int t = 0; t < Ss; ++t) {
        hctx_t_k<<<Bb, 256, 0, stream>>>(H3, beta, hct, t);

        // gates = h_ctx_t @ ta_W (+ lh @ ta_U)
        Seg g0{ hct, ta_W, Hh, 4 * Hh, Hh };
        if (t == 0) {
            gemm_k<128, 128, 8, 8, 1, 0><<<dim3(Bb / 128, (4 * Hh) / 128), 256, 0, stream>>>(
                g0, g0, g0, nullptr, gates, 4 * Hh);
            lstm_ta_k<1><<<(Bb * Hh) / 256, 256, 0, stream>>>(
                gates, ta_b, ta_Wy, yv, lc, lh);
        } else {
            Seg g1{ lh, ta_U, Hh, 4 * Hh, Hh };
            gemm_k<128, 128, 8, 8, 2, 0><<<dim3(Bb / 128, (4 * Hh) / 128), 256, 0, stream>>>(
                g0, g1, g1, nullptr, gates, 4 * Hh);
            lstm_ta_k<0><<<(Bb * Hh) / 256, 256, 0, stream>>>(
                gates, ta_b, ta_Wy, yv, lc, lh);
        }

        y_k<<<Bb, 256, 0, stream>>>(lh, fc_W, fc_b, yv,
                                    (t == Ss - 1) ? (float*)d_out : nullptr);
    }
}

// Round 3
// 3971.397 us; speedup vs baseline: 2.0113x; 2.0113x over previous
//
#include <hip/hip_runtime.h>

// STA-LSTM forward. B=4096 S=16 D=256 HS=HT=512. Output y (B,1) fp32.
// R3: gates GEMMs (481 of 533 GF) moved to split-bf16 MFMA (hi/lo pairs,
//     C = AhBh + AhBl + AlBh, rel err ~2^-17). Weights pre-split+transposed
//     per launch; activations split in producer kernels. m97-style kernel:
//     128x128 tile, BK=32, global_load_lds(16B), ds_read_b128 frags,
//     16x16x32 MFMA. Attention path (A1/A2/softmax/beta/hctx) stays fp32.
// ws: 210 MiB with aliasing (round-2's 204 MiB passed; round-1's 377 crashed).

constexpr int Bb = 4096;
constexpr int Ss = 16;
constexpr int Dd = 256;
constexpr int Hh = 512;   // HS == HT

typedef __attribute__((ext_vector_type(8))) short short8;
typedef __attribute__((ext_vector_type(4))) float f32x4;

__device__ __forceinline__ float sigm(float x) { return 1.0f / (1.0f + expf(-x)); }

__device__ __forceinline__ unsigned short f2bf(float x) {   // RNE fp32->bf16 bits
    unsigned int u = __float_as_uint(x);
    u = (u + 0x7fffu + ((u >> 16) & 1u)) >> 16;
    return (unsigned short)u;
}
__device__ __forceinline__ float bf2f(unsigned short h) {
    return __uint_as_float(((unsigned int)h) << 16);
}
__device__ __forceinline__ void async16(const void* g, void* l) {
    __builtin_amdgcn_global_load_lds(
        (const __attribute__((address_space(1))) void*)g,
        (__attribute__((address_space(3))) void*)l, 16, 0, 0);
}

// ================= split-bf16 MFMA GEMM =================
// C[M,N] = sum_seg (Ah+Al) @ (Bh+Bl)^T-ish: A seg is [M][K] bf16 hi/lo,
// B seg is pre-transposed [N][K] bf16 hi/lo. Drops Al*Bl (O(2^-18)).
struct SegB { const unsigned short* Ah; const unsigned short* Al;
              const unsigned short* Bh; const unsigned short* Bl; int K; };

template<int NSEG>
__global__ __launch_bounds__(256) void gemm_mfma_k(SegB s0, SegB s1,
                                                   float* __restrict__ C, int ldc)
{
    __shared__ __align__(16) unsigned short sA[2][128 * 32];  // [hi/lo][m][k]
    __shared__ __align__(16) unsigned short sB[2][128 * 32];  // [hi/lo][n][k]
    const int tid  = threadIdx.x;
    const int lane = tid & 63;
    const int wv   = tid >> 6;          // 4 waves
    const int wm   = wv & 1, wn = wv >> 1;
    const int row0 = blockIdx.x * 128;
    const int col0 = blockIdx.y * 128;

    f32x4 acc[4][4];
#pragma unroll
    for (int i = 0; i < 4; i++)
#pragma unroll
        for (int j = 0; j < 4; j++) acc[i][j] = (f32x4){0.f, 0.f, 0.f, 0.f};

    const int lrow = lane >> 2;          // 0..15 (row within 16-row chunk)
    const int lcol = (lane & 3) * 8;     // element offset within 32-elem row
    const int q8   = (lane >> 4) * 8;    // frag k-offset
    const int l15  = lane & 15;

#pragma unroll
    for (int sgi = 0; sgi < NSEG; ++sgi) {
        const SegB sg = (sgi == 0) ? s0 : s1;
        const int K = sg.K;
        for (int k0 = 0; k0 < K; k0 += 32) {
            // ---- stage 4 matrices (8 KiB each) via global_load_lds ----
            // chunk c = 16 rows = 1 KiB; wave w stages chunks w and w+4.
#pragma unroll
            for (int half = 0; half < 2; ++half) {
                const int c = wv + half * 4;
                const int r = c * 16 + lrow;
                const size_t gA = (size_t)(row0 + r) * K + k0 + lcol;
                const size_t gB = (size_t)(col0 + r) * K + k0 + lcol;
                const int lo = c * 512 + lrow * 32 + lcol;   // == c*512 + lane*8
                async16(sg.Ah + gA, &sA[0][lo]);
                async16(sg.Al + gA, &sA[1][lo]);
                async16(sg.Bh + gB, &sB[0][lo]);
                async16(sg.Bl + gB, &sB[1][lo]);
            }
            __syncthreads();
            // ---- fragments: A[m=lane&15][k=q8+j], B[k=q8+j][n=lane&15] ----
            short8 ah[4], al[4], bh[4], bl[4];
#pragma unroll
            for (int i = 0; i < 4; i++) {
                const int m = wm * 64 + i * 16 + l15;
                ah[i] = *reinterpret_cast<const short8*>(&sA[0][m * 32 + q8]);
                al[i] = *reinterpret_cast<const short8*>(&sA[1][m * 32 + q8]);
            }
#pragma unroll
            for (int j = 0; j < 4; j++) {
                const int n = wn * 64 + j * 16 + l15;
                bh[j] = *reinterpret_cast<const short8*>(&sB[0][n * 32 + q8]);
                bl[j] = *reinterpret_cast<const short8*>(&sB[1][n * 32 + q8]);
            }
#pragma unroll
            for (int i = 0; i < 4; i++)
#pragma unroll
                for (int j = 0; j < 4; j++) {
                    acc[i][j] = __builtin_amdgcn_mfma_f32_16x16x32_bf16(ah[i], bh[j], acc[i][j], 0, 0, 0);
                    acc[i][j] = __builtin_amdgcn_mfma_f32_16x16x32_bf16(ah[i], bl[j], acc[i][j], 0, 0, 0);
                    acc[i][j] = __builtin_amdgcn_mfma_f32_16x16x32_bf16(al[i], bh[j], acc[i][j], 0, 0, 0);
                }
            __syncthreads();
        }
    }
    // ---- epilogue: C/D layout col=lane&15, row=(lane>>4)*4+r ----
#pragma unroll
    for (int i = 0; i < 4; i++) {
#pragma unroll
        for (int j = 0; j < 4; j++) {
            const int col = col0 + wn * 64 + j * 16 + l15;
#pragma unroll
            for (int r = 0; r < 4; r++) {
                const int row = row0 + wm * 64 + i * 16 + (lane >> 4) * 4 + r;
                C[(size_t)row * ldc + col] = acc[i][j][r];
            }
        }
    }
}

// ============ weight prep: W[K][N] fp32 -> Th,Tl [N][K] bf16 ============
__global__ __launch_bounds__(256) void splitT_k(const float* __restrict__ W,
                                                unsigned short* __restrict__ Th,
                                                unsigned short* __restrict__ Tl,
                                                int Kd, int Nd)
{
    __shared__ float tile[32][33];
    const int bk = blockIdx.x * 32, bn = blockIdx.y * 32;
    const int tid = threadIdx.x;
    const int r = tid >> 3, c4 = (tid & 7) * 4;
    const float4 v = *reinterpret_cast<const float4*>(&W[(size_t)(bk + r) * Nd + bn + c4]);
    tile[r][c4 + 0] = v.x; tile[r][c4 + 1] = v.y;
    tile[r][c4 + 2] = v.z; tile[r][c4 + 3] = v.w;
    __syncthreads();
    const int n = r, k4 = c4;
    ushort4 hq, lq;
    unsigned short* hp = (unsigned short*)&hq;
    unsigned short* lp = (unsigned short*)&lq;
#pragma unroll
    for (int q = 0; q < 4; q++) {
        float x = tile[k4 + q][n];
        unsigned short h = f2bf(x);
        hp[q] = h;
        lp[q] = f2bf(x - bf2f(h));
    }
    *reinterpret_cast<ushort4*>(&Th[(size_t)(bn + n) * Kd + bk + k4]) = hq;
    *reinterpret_cast<ushort4*>(&Tl[(size_t)(bn + n) * Kd + bk + k4]) = lq;
}

// ================= fp32 multi-segment GEMM (attention path) =================
struct Seg { const float* A; const float* Bm; int lda; int ldb; int K; };

template<int BM, int BN, int TM, int TN, int NSEG, int EPI>
__global__ __launch_bounds__(256) void gemm_k(Seg s0, Seg s1, Seg s2,
                                              const float* __restrict__ bias,
                                              float* __restrict__ C, int ldc)
{
    __shared__ float As[16][BM + 4];
    __shared__ float Bs[16][BN + 4];
    const int tid  = threadIdx.x;
    const int row0 = blockIdx.x * BM;
    const int col0 = blockIdx.y * BN;
    constexpr int NTX = BN / TN;
    const int tx = tid % NTX;
    const int ty = tid / NTX;

    float acc[TM][TN];
#pragma unroll
    for (int i = 0; i < TM; i++)
#pragma unroll
        for (int j = 0; j < TN; j++) acc[i][j] = 0.0f;

#pragma unroll
    for (int sgi = 0; sgi < NSEG; ++sgi) {
        Seg sg = (sgi == 0) ? s0 : ((sgi == 1) ? s1 : s2);
        const int nkt = sg.K / 16;
        for (int kt = 0; kt < nkt; ++kt) {
            const int k0 = kt * 16;
            constexpr int ACNT = (BM * 4) / 256;
#pragma unroll
            for (int i = 0; i < ACNT; i++) {
                int idx = tid + i * 256;
                int r = idx >> 2, kq = idx & 3;
                const float4 v = *reinterpret_cast<const float4*>(
                    sg.A + (size_t)(row0 + r) * sg.lda + k0 + kq * 4);
                As[kq * 4 + 0][r] = v.x;
                As[kq * 4 + 1][r] = v.y;
                As[kq * 4 + 2][r] = v.z;
                As[kq * 4 + 3][r] = v.w;
            }
            constexpr int BCNT = (BN * 4) / 256;
#pragma unroll
            for (int i = 0; i < BCNT; i++) {
                int idx = tid + i * 256;
                int k = idx / (BN / 4), nq = idx % (BN / 4);
                const float4 v = *reinterpret_cast<const float4*>(
                    sg.Bm + (size_t)(k0 + k) * sg.ldb + col0 + nq * 4);
                *reinterpret_cast<float4*>(&Bs[k][nq * 4]) = v;
            }
            __syncthreads();
#pragma unroll
            for (int k = 0; k < 16; k++) {
                float a_[TM], b_[TN];
#pragma unroll
                for (int i = 0; i < TM; i++) a_[i] = As[k][ty * TM + i];
#pragma unroll
                for (int j = 0; j < TN; j++) b_[j] = Bs[k][tx * TN + j];
#pragma unroll
                for (int i = 0; i < TM; i++)
#pragma unroll
                    for (int j = 0; j < TN; j++)
                        acc[i][j] = fmaf(a_[i], b_[j], acc[i][j]);
            }
            __syncthreads();
        }
    }

#pragma unroll
    for (int i = 0; i < TM; i++) {
        int r = row0 + ty * TM + i;
#pragma unroll
        for (int j = 0; j < TN; j++) {
            int cc = col0 + tx * TN + j;
            float v = acc[i][j];
            if (EPI == 1) v = tanhf(v + bias[cc]);
            C[(size_t)r * ldc + cc] = v;
        }
    }
}

// ---------------- init: y0 = X[:,0,255] ----------------
__global__ __launch_bounds__(256) void init_k(const float* __restrict__ X,
                                              float* __restrict__ yv)
{
    int idx = blockIdx.x * 256 + threadIdx.x;
    if (idx < Bb) yv[idx] = X[(size_t)idx * Ss * Dd + (Dd - 1)];
}

// ------- softmax over D, scale by x_t, emit bf16 hi/lo xt -------
__global__ __launch_bounds__(256) void softmax_xt_k(const float* __restrict__ a,
                                                    const float* __restrict__ X,
                                                    unsigned short* __restrict__ xh,
                                                    unsigned short* __restrict__ xl,
                                                    int t)
{
    int b = blockIdx.x, tid = threadIdx.x;
    __shared__ float red[256];
    float v = a[(size_t)b * Dd + tid];
    red[tid] = v; __syncthreads();
    for (int s = 128; s > 0; s >>= 1) {
        if (tid < s) red[tid] = fmaxf(red[tid], red[tid + s]);
        __syncthreads();
    }
    float mx = red[0]; __syncthreads();
    float e = expf(v - mx);
    red[tid] = e; __syncthreads();
    for (int s = 128; s > 0; s >>= 1) {
        if (tid < s) red[tid] += red[tid + s];
        __syncthreads();
    }
    float inv = 1.0f / red[0];
    float xv = e * inv * X[(size_t)b * Ss * Dd + (size_t)t * Dd + tid];
    unsigned short h = f2bf(xv);
    xh[(size_t)b * Dd + tid] = h;
    xl[(size_t)b * Dd + tid] = f2bf(xv - bf2f(h));
}

// ------- sa LSTM pointwise: c in-place, h -> fp32 H3 + bf16 hi/lo -------
template<int ZC>
__global__ __launch_bounds__(256) void lstm_sa_k(const float* __restrict__ gates,
                                                 const float* __restrict__ bias,
                                                 float* __restrict__ c_io,
                                                 float* __restrict__ h_out,
                                                 unsigned short* __restrict__ hh,
                                                 unsigned short* __restrict__ hl)
{
    int idx = blockIdx.x * 256 + threadIdx.x;   // Bb*Hh
    int b = idx >> 9, j = idx & 511;
    const float* g = gates + (size_t)b * 4 * Hh;
    float gi = g[j]          + bias[j];
    float gf = g[Hh + j]     + bias[Hh + j];
    float gg = g[2 * Hh + j] + bias[2 * Hh + j];
    float go = g[3 * Hh + j] + bias[3 * Hh + j];
    float i_ = sigm(gi), f_ = sigm(gf), gv = tanhf(gg), o_ = sigm(go);
    float cp = ZC ? 0.0f : c_io[idx];
    float c = f_ * cp + i_ * gv;
    c_io[idx] = c;
    float h = o_ * tanhf(c);
    h_out[idx] = h;
    unsigned short hb = f2bf(h);
    hh[idx] = hb;
    hl[idx] = f2bf(h - bf2f(hb));
}

// ------- ta LSTM pointwise (+rank-1 y_prev*ta_Wy); lh -> fp32 + hi/lo -------
template<int ZC>
__global__ __launch_bounds__(256) void lstm_ta_k(const float* __restrict__ gates,
                                                 const float* __restrict__ bias,
                                                 const float* __restrict__ wy,
                                                 const float* __restrict__ yv,
                                                 float* __restrict__ c_io,
                                                 float* __restrict__ h_out,
                                                 unsigned short* __restrict__ hh,
                                                 unsigned short* __restrict__ hl)
{
    int idx = blockIdx.x * 256 + threadIdx.x;
    int b = idx >> 9, j = idx & 511;
    const float* g = gates + (size_t)b * 4 * Hh;
    float yb = yv[b];
    float gi = g[j]          + bias[j]          + yb * wy[j];
    float gf = g[Hh + j]     + bias[Hh + j]     + yb * wy[Hh + j];
    float gg = g[2 * Hh + j] + bias[2 * Hh + j] + yb * wy[2 * Hh + j];
    float go = g[3 * Hh + j] + bias[3 * Hh + j] + yb * wy[3 * Hh + j];
    float i_ = sigm(gi), f_ = sigm(gf), gv = tanhf(gg), o_ = sigm(go);
    float cp = ZC ? 0.0f : c_io[idx];
    float c = f_ * cp + i_ * gv;
    c_io[idx] = c;
    float h = o_ * tanhf(c);
    h_out[idx] = h;
    unsigned short hb = f2bf(h);
    hh[idx] = hb;
    hl[idx] = f2bf(h - bf2f(hb));
}

// ------- beta = softmax(tanh(h_t @ ta_Wa + ta_ba) @ ta_Va); s0==0 -------
__global__ __launch_bounds__(256) void beta_k(const float* __restrict__ H3,
                                              const float* __restrict__ taWa,
                                              const float* __restrict__ taba,
                                              const float* __restrict__ taVa,
                                              float* __restrict__ beta)
{
    int bx = blockIdx.x, t = blockIdx.y, tid = threadIdx.x;
    __shared__ float Was[512 * 16];
    __shared__ float Vas[256];
    __shared__ float tt[16][17];
    __shared__ float lt[16][17];
    for (int i = tid; i < 512 * 16; i += 256) Was[i] = taWa[i];
    Vas[tid] = taVa[tid];
    __syncthreads();
    int r = tid >> 4, n = tid & 15;
    int b = bx * 16 + r;
    const float* hrow = H3 + ((size_t)t * Bb + b) * Hh;
    float acc = taba[n];
    for (int k = 0; k < 512; k++) acc = fmaf(hrow[k], Was[k * 16 + n], acc);
    tt[r][n] = tanhf(acc);
    __syncthreads();
    float l = 0.0f;
#pragma unroll
    for (int m = 0; m < 16; m++) l = fmaf(tt[r][m], Vas[m * 16 + n], l);
    lt[r][n] = l;
    __syncthreads();
    float mx = -1e30f;
#pragma unroll
    for (int m = 0; m < 16; m++) mx = fmaxf(mx, lt[r][m]);
    float sum = 0.0f;
#pragma unroll
    for (int m = 0; m < 16; m++) sum += expf(lt[r][m] - mx);
    beta[((size_t)t * Bb + b) * 16 + n] = expf(l - mx) / sum;
}

// ------- h_ctx for one t, emitted as bf16 hi/lo -------
__global__ __launch_bounds__(256) void hctx_t_k(const float* __restrict__ H3,
                                                const float* __restrict__ beta,
                                                unsigned short* __restrict__ hcth,
                                                unsigned short* __restrict__ hctl,
                                                int t)
{
    int b = blockIdx.x, tid = threadIdx.x;
    __shared__ float Hs[16][513];
    __shared__ float bs[16];
    for (int i = tid; i < 16 * 512; i += 256) {
        int s = i >> 9, h = i & 511;
        Hs[s][h] = H3[((size_t)s * Bb + b) * Hh + h];
    }
    if (tid < 16) bs[tid] = beta[((size_t)t * Bb + b) * 16 + tid];
    __syncthreads();
    for (int h = tid; h < Hh; h += 256) {
        float acc = 0.0f;
#pragma unroll
        for (int s = 0; s < 16; s++) acc = fmaf(bs[s], Hs[s][h], acc);
        unsigned short hb = f2bf(acc);
        hcth[(size_t)b * Hh + h] = hb;
        hctl[(size_t)b * Hh + h] = f2bf(acc - bf2f(hb));
    }
}

// ---------------- y = lh @ fc_W.T + fc_b ----------------
__global__ __launch_bounds__(256) void y_k(const float* __restrict__ lh,
                                           const float* __restrict__ fcW,
                                           const float* __restrict__ fcb,
                                           float* __restrict__ yv,
                                           float* __restrict__ outp)
{
    int b = blockIdx.x, tid = threadIdx.x;
    __shared__ float red[256];
    float p = lh[(size_t)b * Hh + tid] * fcW[tid]
            + lh[(size_t)b * Hh + 256 + tid] * fcW[256 + tid];
    red[tid] = p; __syncthreads();
    for (int s = 128; s > 0; s >>= 1) {
        if (tid < s) red[tid] += red[tid + s];
        __syncthreads();
    }
    if (tid == 0) {
        float y = red[0] + fcb[0];
        yv[b] = y;
        if (outp) outp[b] = y;
    }
}

extern "C" void kernel_launch(void* const* d_in, const int* in_sizes, int n_in,
                              void* d_out, int out_size, void* d_ws, size_t ws_size,
                              hipStream_t stream)
{
    (void)in_sizes; (void)n_in; (void)out_size; (void)ws_size;
    const float* X     = (const float*)d_in[0];
    const float* sa_W  = (const float*)d_in[1];
    const float* sa_U  = (const float*)d_in[2];
    const float* sa_b  = (const float*)d_in[3];
    const float* sa_Wa = (const float*)d_in[4];
    const float* sa_Ua = (const float*)d_in[5];
    const float* sa_ba = (const float*)d_in[6];
    const float* sa_Va = (const float*)d_in[7];
    const float* ta_Wa = (const float*)d_in[8];
    // d_in[9] = ta_Ua : multiplied by s0 == 0 -> unused
    const float* ta_ba = (const float*)d_in[10];
    const float* ta_Va = (const float*)d_in[11];
    const float* ta_W  = (const float*)d_in[12];
    const float* ta_U  = (const float*)d_in[13];
    const float* ta_b  = (const float*)d_in[14];
    const float* ta_Wy = (const float*)d_in[15];
    const float* fc_W  = (const float*)d_in[16];
    const float* fc_b  = (const float*)d_in[17];

    char* base = (char*)d_ws;
    size_t off = 0;
    auto alloc = [&](size_t bytes) {
        void* p = base + off; off += (bytes + 255) & ~(size_t)255; return p;
    };
    const size_t BH = (size_t)Bb * Hh;          // 2M elems
    float* gates = (float*)alloc(BH * 4 * 4);   // 32 MiB (also hosts tmp+avxt)
    float* tmp   = gates;                        // 4 MiB window (dead before gates write)
    float* avxt  = gates + (size_t)Bb * Dd;      // next 4 MiB window
    float* H3    = (float*)alloc((size_t)Ss * BH * 4);          // 128 MiB
    float* cbuf  = (float*)alloc(BH * 4);        // 8 MiB (sa c; dead in ta -> lh pair)
    float* lh    = (float*)alloc(BH * 4);        // 8 MiB
    float* lc    = (float*)alloc(BH * 4);        // 8 MiB
    unsigned short* xth = (unsigned short*)alloc((size_t)Bb * Dd * 2);  // 2 MiB
    unsigned short* xtl = (unsigned short*)alloc((size_t)Bb * Dd * 2);  // 2 MiB
    unsigned short* hh  = (unsigned short*)alloc(BH * 2);               // 4 MiB
    unsigned short* hl  = (unsigned short*)alloc(BH * 2);               // 4 MiB
    unsigned short* saWth = (unsigned short*)alloc((size_t)Dd * 4 * Hh * 2);
    unsigned short* saWtl = (unsigned short*)alloc((size_t)Dd * 4 * Hh * 2);
    unsigned short* saUth = (unsigned short*)alloc((size_t)Hh * 4 * Hh * 2);
    unsigned short* saUtl = (unsigned short*)alloc((size_t)Hh * 4 * Hh * 2);
    unsigned short* taWth = (unsigned short*)alloc((size_t)Hh * 4 * Hh * 2);
    unsigned short* taWtl = (unsigned short*)alloc((size_t)Hh * 4 * Hh * 2);
    unsigned short* taUth = (unsigned short*)alloc((size_t)Hh * 4 * Hh * 2);
    unsigned short* taUtl = (unsigned short*)alloc((size_t)Hh * 4 * Hh * 2);
    float* yv = (float*)alloc((size_t)Bb * 4);
    // aliases (regions dead at time of reuse):
    float* beta = (float*)xth;                   // 4 MiB over xth+xtl (ta phase)
    unsigned short* hcth = hh;                   // ta phase
    unsigned short* hctl = hl;
    unsigned short* lhh = (unsigned short*)cbuf; // ta phase (cbuf dead)
    unsigned short* lhl = (unsigned short*)cbuf + BH;
    // total ~210 MiB

    // ---- weight prep: split + transpose to [N][K] bf16 hi/lo ----
    splitT_k<<<dim3(Dd / 32, (4 * Hh) / 32), 256, 0, stream>>>(sa_W, saWth, saWtl, Dd, 4 * Hh);
    splitT_k<<<dim3(Hh / 32, (4 * Hh) / 32), 256, 0, stream>>>(sa_U, saUth, saUtl, Hh, 4 * Hh);
    splitT_k<<<dim3(Hh / 32, (4 * Hh) / 32), 256, 0, stream>>>(ta_W, taWth, taWtl, Hh, 4 * Hh);
    splitT_k<<<dim3(Hh / 32, (4 * Hh) / 32), 256, 0, stream>>>(ta_U, taUth, taUtl, Hh, 4 * Hh);
    init_k<<<dim3(16), 256, 0, stream>>>(X, yv);

    const dim3 ggrid(Bb / 128, (4 * Hh) / 128);   // 32 x 16

    // ---- spatial-attention LSTM ----
    for (int t = 0; t < Ss; ++t) {
        const float* h_prev = (t == 0) ? nullptr : (H3 + (size_t)(t - 1) * BH);

        // tmp = tanh(x_t @ sa_Wa + h @ Ua[:HS] + c @ Ua[HS:] + sa_ba)  [fp32]
        Seg s0{ X + (size_t)t * Dd, sa_Wa, Ss * Dd, Dd, Dd };
        if (t == 0) {
            gemm_k<64, 64, 4, 4, 1, 1><<<dim3(Bb / 64, Dd / 64), 256, 0, stream>>>(
                s0, s0, s0, sa_ba, tmp, Dd);
        } else {
            Seg s1{ h_prev, sa_Ua, Hh, Dd, Hh };
            Seg s2{ cbuf, sa_Ua + (size_t)Hh * Dd, Hh, Dd, Hh };
            gemm_k<64, 64, 4, 4, 3, 1><<<dim3(Bb / 64, Dd / 64), 256, 0, stream>>>(
                s0, s1, s2, sa_ba, tmp, Dd);
        }

        // av = tmp @ sa_Va  [fp32]
        Seg v0{ tmp, sa_Va, Dd, Dd, Dd };
        gemm_k<64, 64, 4, 4, 1, 0><<<dim3(Bb / 64, Dd / 64), 256, 0, stream>>>(
            v0, v0, v0, nullptr, avxt, Dd);

        softmax_xt_k<<<Bb, 256, 0, stream>>>(avxt, X, xth, xtl, t);

        // gates = xt @ sa_W (+ h @ sa_U)  [split-bf16 MFMA]
        SegB g0{ xth, xtl, saWth, saWtl, Dd };
        if (t == 0) {
            gemm_mfma_k<1><<<ggrid, 256, 0, stream>>>(g0, g0, gates, 4 * Hh);
            lstm_sa_k<1><<<(int)(BH / 256), 256, 0, stream>>>(
                gates, sa_b, cbuf, H3 + (size_t)t * BH, hh, hl);
        } else {
            SegB g1{ hh, hl, saUth, saUtl, Hh };
            gemm_mfma_k<2><<<ggrid, 256, 0, stream>>>(g0, g1, gates, 4 * Hh);
            lstm_sa_k<0><<<(int)(BH / 256), 256, 0, stream>>>(
                gates, sa_b, cbuf, H3 + (size_t)t * BH, hh, hl);
        }
    }

    // ---- temporal attention weights (all steps; s0 == 0) ----
    beta_k<<<dim3(Bb / 16, Ss), 256, 0, stream>>>(H3, ta_Wa, ta_ba, ta_Va, beta);

    // ---- temporal LSTM ----
    for (int t = 0; t < Ss; ++t) {
        hctx_t_k<<<Bb, 256, 0, stream>>>(H3, beta, hcth, hctl, t);

        // gates = h_ctx_t @ ta_W (+ lh @ ta_U)  [split-bf16 MFMA]
        SegB g0{ hcth, hctl, taWth, taWtl, Hh };
        if (t == 0) {
            gemm_mfma_k<1><<<ggrid, 256, 0, stream>>>(g0, g0, gates, 4 * Hh);
            lstm_ta_k<1><<<(int)(BH / 256), 256, 0, stream>>>(
                gates, ta_b, ta_Wy, yv, lc, lh, lhh, lhl);
        } else {
            SegB g1{ lhh, lhl, taUth, taUtl, Hh };
            gemm_mfma_k<2><<<ggrid, 256, 0, stream>>>(g0, g1, gates, 4 * Hh);
            lstm_ta_k<0><<<(int)(BH / 256), 256, 0, stream>>>(
                gates, ta_b, ta_Wy, yv, lc, lh, lhh, lhl);
        }

        y_k<<<Bb, 256, 0, stream>>>(lh, fc_W, fc_b, yv,
                                    (t == Ss - 1) ? (float*)d_out : nullptr);
    }
}

// Round 4
// 3229.889 us; speedup vs baseline: 2.4730x; 1.2296x over previous
//
#include <hip/hip_runtime.h>

// STA-LSTM forward. B=4096 S=16 D=256 HS=HT=512. Output y (B,1) fp32.
// R4: ALL GEMMs on split-bf16 MFMA (C = AhBh + AhBl + AlBh, rel ~2^-17).
//     Generic tiled kernel (templated BM/BN, per-seg lda/ldb):
//       A1: NSEG=3 (x_t,h,c @ Wa|Ua), 64x64 tiles, tanh+split epilogue
//       A2: NSEG=1 (tmp @ Va), 64x64
//       gates: NSEG=2 (xt@saW + h@saU / hctx@taW + lh@taU), 128x128
//     H3 stored as bf16 hi/lo pairs (fp32-equiv precision for beta/hctx).
//     X slices pre-split (init_k for t=0; piggybacked on lstm_sa_k for t+1).
// ws: ~219.5 MiB (round-3's 210 passed; round-1's 377 crashed).

constexpr int Bb = 4096;
constexpr int Ss = 16;
constexpr int Dd = 256;
constexpr int Hh = 512;   // HS == HT

typedef __attribute__((ext_vector_type(8))) short short8;
typedef __attribute__((ext_vector_type(4))) float f32x4;

__device__ __forceinline__ float sigm(float x) { return 1.0f / (1.0f + expf(-x)); }

__device__ __forceinline__ unsigned short f2bf(float x) {   // RNE fp32->bf16 bits
    unsigned int u = __float_as_uint(x);
    u = (u + 0x7fffu + ((u >> 16) & 1u)) >> 16;
    return (unsigned short)u;
}
__device__ __forceinline__ float bf2f(unsigned short h) {
    return __uint_as_float(((unsigned int)h) << 16);
}
__device__ __forceinline__ void async16(const void* g, void* l) {
    __builtin_amdgcn_global_load_lds(
        (const __attribute__((address_space(1))) void*)g,
        (__attribute__((address_space(3))) void*)l, 16, 0, 0);
}

// ================= split-bf16 MFMA GEMM (generic) =================
// C[M,N] = sum_seg (Ah+Al)[M,K] @ (Bh+Bl)[N,K]^T, dropping Al*Bl.
// EPI=0: store fp32 C. EPI=1: v=tanh(acc+bias[col]); split-store to Th/Tl.
struct SegB { const unsigned short* Ah; const unsigned short* Al;
              const unsigned short* Bh; const unsigned short* Bl;
              int lda; int ldb; int K; };

template<int BM, int BN, int NSEG, int EPI>
__global__ __launch_bounds__(256) void gemm_mfma_k(
    SegB s0, SegB s1, SegB s2,
    const float* __restrict__ bias,
    float* __restrict__ C,
    unsigned short* __restrict__ Th, unsigned short* __restrict__ Tl,
    int ldc)
{
    constexpr int WM = BM / 2, WN = BN / 2;
    constexpr int FI = WM / 16, FJ = WN / 16;
    __shared__ __align__(16) unsigned short sA[2][BM * 32];  // [hi/lo][m][k]
    __shared__ __align__(16) unsigned short sB[2][BN * 32];  // [hi/lo][n][k]
    const int tid  = threadIdx.x;
    const int lane = tid & 63;
    const int wv   = tid >> 6;          // 4 waves, 2x2
    const int wm   = wv & 1, wn = wv >> 1;
    const int row0 = blockIdx.x * BM;
    const int col0 = blockIdx.y * BN;

    f32x4 acc[FI][FJ];
#pragma unroll
    for (int i = 0; i < FI; i++)
#pragma unroll
        for (int j = 0; j < FJ; j++) acc[i][j] = (f32x4){0.f, 0.f, 0.f, 0.f};

    const int lrow = lane >> 2;          // 0..15 row within 16-row chunk
    const int lcol = (lane & 3) * 8;     // element offset within 32-elem row
    const int q8   = (lane >> 4) * 8;    // frag k-offset
    const int l15  = lane & 15;

#pragma unroll
    for (int sgi = 0; sgi < NSEG; ++sgi) {
        const SegB sg = (sgi == 0) ? s0 : ((sgi == 1) ? s1 : s2);
        const int K = sg.K;
        for (int k0 = 0; k0 < K; k0 += 32) {
            // ---- stage tiles via global_load_lds (16B chunks) ----
#pragma unroll
            for (int c = wv; c < BM / 16; c += 4) {
                const int r = c * 16 + lrow;
                const size_t gA = (size_t)(row0 + r) * sg.lda + k0 + lcol;
                const int lo = c * 512 + lane * 8;
                async16(sg.Ah + gA, &sA[0][lo]);
                async16(sg.Al + gA, &sA[1][lo]);
            }
#pragma unroll
            for (int c = wv; c < BN / 16; c += 4) {
                const int r = c * 16 + lrow;
                const size_t gB = (size_t)(col0 + r) * sg.ldb + k0 + lcol;
                const int lo = c * 512 + lane * 8;
                async16(sg.Bh + gB, &sB[0][lo]);
                async16(sg.Bl + gB, &sB[1][lo]);
            }
            __syncthreads();
            // ---- fragments ----
            short8 ah[FI], al[FI], bh[FJ], bl[FJ];
#pragma unroll
            for (int i = 0; i < FI; i++) {
                const int m = wm * WM + i * 16 + l15;
                ah[i] = *reinterpret_cast<const short8*>(&sA[0][m * 32 + q8]);
                al[i] = *reinterpret_cast<const short8*>(&sA[1][m * 32 + q8]);
            }
#pragma unroll
            for (int j = 0; j < FJ; j++) {
                const int n = wn * WN + j * 16 + l15;
                bh[j] = *reinterpret_cast<const short8*>(&sB[0][n * 32 + q8]);
                bl[j] = *reinterpret_cast<const short8*>(&sB[1][n * 32 + q8]);
            }
#pragma unroll
            for (int i = 0; i < FI; i++)
#pragma unroll
                for (int j = 0; j < FJ; j++) {
                    acc[i][j] = __builtin_amdgcn_mfma_f32_16x16x32_bf16(ah[i], bh[j], acc[i][j], 0, 0, 0);
                    acc[i][j] = __builtin_amdgcn_mfma_f32_16x16x32_bf16(ah[i], bl[j], acc[i][j], 0, 0, 0);
                    acc[i][j] = __builtin_amdgcn_mfma_f32_16x16x32_bf16(al[i], bh[j], acc[i][j], 0, 0, 0);
                }
            __syncthreads();
        }
    }
    // ---- epilogue: C/D layout col=lane&15, row=(lane>>4)*4+r ----
#pragma unroll
    for (int i = 0; i < FI; i++) {
#pragma unroll
        for (int j = 0; j < FJ; j++) {
            const int col = col0 + wn * WN + j * 16 + l15;
#pragma unroll
            for (int r = 0; r < 4; r++) {
                const int row = row0 + wm * WM + i * 16 + (lane >> 4) * 4 + r;
                float v = acc[i][j][r];
                if (EPI == 1) {
                    v = tanhf(v + bias[col]);
                    unsigned short hb = f2bf(v);
                    Th[(size_t)row * ldc + col] = hb;
                    Tl[(size_t)row * ldc + col] = f2bf(v - bf2f(hb));
                } else {
                    C[(size_t)row * ldc + col] = v;
                }
            }
        }
    }
}

// ============ weight prep: W[K][N] fp32 -> Th,Tl [N][K] bf16 ============
__global__ __launch_bounds__(256) void splitT_k(const float* __restrict__ W,
                                                unsigned short* __restrict__ Th,
                                                unsigned short* __restrict__ Tl,
                                                int Kd, int Nd)
{
    __shared__ float tile[32][33];
    const int bk = blockIdx.x * 32, bn = blockIdx.y * 32;
    const int tid = threadIdx.x;
    const int r = tid >> 3, c4 = (tid & 7) * 4;
    const float4 v = *reinterpret_cast<const float4*>(&W[(size_t)(bk + r) * Nd + bn + c4]);
    tile[r][c4 + 0] = v.x; tile[r][c4 + 1] = v.y;
    tile[r][c4 + 2] = v.z; tile[r][c4 + 3] = v.w;
    __syncthreads();
    const int n = r, k4 = c4;
    ushort4 hq, lq;
    unsigned short* hp = (unsigned short*)&hq;
    unsigned short* lp = (unsigned short*)&lq;
#pragma unroll
    for (int q = 0; q < 4; q++) {
        float x = tile[k4 + q][n];
        unsigned short h = f2bf(x);
        hp[q] = h;
        lp[q] = f2bf(x - bf2f(h));
    }
    *reinterpret_cast<ushort4*>(&Th[(size_t)(bn + n) * Kd + bk + k4]) = hq;
    *reinterpret_cast<ushort4*>(&Tl[(size_t)(bn + n) * Kd + bk + k4]) = lq;
}

// -------- init: y0 = X[:,0,255]; split X[:,0,:] to xsh/xsl --------
__global__ __launch_bounds__(256) void init_k(const float* __restrict__ X,
                                              unsigned short* __restrict__ xsh,
                                              unsigned short* __restrict__ xsl,
                                              float* __restrict__ yv)
{
    int idx = blockIdx.x * 256 + threadIdx.x;   // over Bb*Dd
    int b = idx >> 8, d = idx & 255;
    float xv = X[(size_t)b * (Ss * Dd) + d];    // t = 0
    unsigned short hb = f2bf(xv);
    xsh[idx] = hb;
    xsl[idx] = f2bf(xv - bf2f(hb));
    if (d == Dd - 1) yv[b] = xv;
}

// ------- softmax over D, scale by x_t, emit bf16 hi/lo xt -------
__global__ __launch_bounds__(256) void softmax_xt_k(const float* __restrict__ a,
                                                    const float* __restrict__ X,
                                                    unsigned short* __restrict__ xh,
                                                    unsigned short* __restrict__ xl,
                                                    int t)
{
    int b = blockIdx.x, tid = threadIdx.x;
    __shared__ float red[256];
    float v = a[(size_t)b * Dd + tid];
    red[tid] = v; __syncthreads();
    for (int s = 128; s > 0; s >>= 1) {
        if (tid < s) red[tid] = fmaxf(red[tid], red[tid + s]);
        __syncthreads();
    }
    float mx = red[0]; __syncthreads();
    float e = expf(v - mx);
    red[tid] = e; __syncthreads();
    for (int s = 128; s > 0; s >>= 1) {
        if (tid < s) red[tid] += red[tid + s];
        __syncthreads();
    }
    float inv = 1.0f / red[0];
    float xv = e * inv * X[(size_t)b * Ss * Dd + (size_t)t * Dd + tid];
    unsigned short h = f2bf(xv);
    xh[(size_t)b * Dd + tid] = h;
    xl[(size_t)b * Dd + tid] = f2bf(xv - bf2f(h));
}

// ------- sa LSTM pointwise: c fp32 in-place + bf16 h/c hi/lo;
//         optionally piggyback the split of X[:,tnext,:] -------
template<int ZC, int SPLITX>
__global__ __launch_bounds__(256) void lstm_sa_k(
    const float* __restrict__ gates, const float* __restrict__ bias,
    float* __restrict__ c_io,
    unsigned short* __restrict__ h3h, unsigned short* __restrict__ h3l,
    unsigned short* __restrict__ ch, unsigned short* __restrict__ cl,
    const float* __restrict__ X,
    unsigned short* __restrict__ xsh, unsigned short* __restrict__ xsl,
    int tnext)
{
    int idx = blockIdx.x * 256 + threadIdx.x;   // Bb*Hh
    int b = idx >> 9, j = idx & 511;
    const float* g = gates + (size_t)b * 4 * Hh;
    float gi = g[j]          + bias[j];
    float gf = g[Hh + j]     + bias[Hh + j];
    float gg = g[2 * Hh + j] + bias[2 * Hh + j];
    float go = g[3 * Hh + j] + bias[3 * Hh + j];
    float i_ = sigm(gi), f_ = sigm(gf), gv = tanhf(gg), o_ = sigm(go);
    float cp = ZC ? 0.0f : c_io[idx];
    float c = f_ * cp + i_ * gv;
    c_io[idx] = c;
    unsigned short cb = f2bf(c);
    ch[idx] = cb;
    cl[idx] = f2bf(c - bf2f(cb));
    float h = o_ * tanhf(c);
    unsigned short hb = f2bf(h);
    h3h[idx] = hb;
    h3l[idx] = f2bf(h - bf2f(hb));
    if (SPLITX && j < Dd) {
        float xv = X[(size_t)b * (Ss * Dd) + (size_t)tnext * Dd + j];
        unsigned short xb = f2bf(xv);
        xsh[(size_t)b * Dd + j] = xb;
        xsl[(size_t)b * Dd + j] = f2bf(xv - bf2f(xb));
    }
}

// ------- ta LSTM pointwise (+rank-1 y_prev*ta_Wy); lh fp32 + hi/lo -------
template<int ZC>
__global__ __launch_bounds__(256) void lstm_ta_k(const float* __restrict__ gates,
                                                 const float* __restrict__ bias,
                                                 const float* __restrict__ wy,
                                                 const float* __restrict__ yv,
                                                 float* __restrict__ c_io,
                                                 float* __restrict__ h_out,
                                                 unsigned short* __restrict__ hh,
                                                 unsigned short* __restrict__ hl)
{
    int idx = blockIdx.x * 256 + threadIdx.x;
    int b = idx >> 9, j = idx & 511;
    const float* g = gates + (size_t)b * 4 * Hh;
    float yb = yv[b];
    float gi = g[j]          + bias[j]          + yb * wy[j];
    float gf = g[Hh + j]     + bias[Hh + j]     + yb * wy[Hh + j];
    float gg = g[2 * Hh + j] + bias[2 * Hh + j] + yb * wy[2 * Hh + j];
    float go = g[3 * Hh + j] + bias[3 * Hh + j] + yb * wy[3 * Hh + j];
    float i_ = sigm(gi), f_ = sigm(gf), gv = tanhf(gg), o_ = sigm(go);
    float cp = ZC ? 0.0f : c_io[idx];
    float c = f_ * cp + i_ * gv;
    c_io[idx] = c;
    float h = o_ * tanhf(c);
    h_out[idx] = h;
    unsigned short hb = f2bf(h);
    hh[idx] = hb;
    hl[idx] = f2bf(h - bf2f(hb));
}

// ------- beta = softmax(tanh(h_t @ ta_Wa + ta_ba) @ ta_Va); s0==0 -------
// H3 is bf16 hi/lo pairs (fp32-equivalent on reconstruct).
__global__ __launch_bounds__(256) void beta_k(const unsigned short* __restrict__ H3h,
                                              const unsigned short* __restrict__ H3l,
                                              const float* __restrict__ taWa,
                                              const float* __restrict__ taba,
                                              const float* __restrict__ taVa,
                                              float* __restrict__ beta)
{
    int bx = blockIdx.x, t = blockIdx.y, tid = threadIdx.x;
    __shared__ float Was[512 * 16];
    __shared__ float Vas[256];
    __shared__ float tt[16][17];
    __shared__ float lt[16][17];
    for (int i = tid; i < 512 * 16; i += 256) Was[i] = taWa[i];
    Vas[tid] = taVa[tid];
    __syncthreads();
    int r = tid >> 4, n = tid & 15;
    int b = bx * 16 + r;
    const unsigned short* hrh = H3h + ((size_t)t * Bb + b) * Hh;
    const unsigned short* hrl = H3l + ((size_t)t * Bb + b) * Hh;
    float acc = taba[n];
    for (int k = 0; k < 512; k++) {
        float hk = bf2f(hrh[k]) + bf2f(hrl[k]);
        acc = fmaf(hk, Was[k * 16 + n], acc);
    }
    tt[r][n] = tanhf(acc);
    __syncthreads();
    float l = 0.0f;
#pragma unroll
    for (int m = 0; m < 16; m++) l = fmaf(tt[r][m], Vas[m * 16 + n], l);
    lt[r][n] = l;
    __syncthreads();
    float mx = -1e30f;
#pragma unroll
    for (int m = 0; m < 16; m++) mx = fmaxf(mx, lt[r][m]);
    float sum = 0.0f;
#pragma unroll
    for (int m = 0; m < 16; m++) sum += expf(lt[r][m] - mx);
    beta[((size_t)t * Bb + b) * 16 + n] = expf(l - mx) / sum;
}

// ------- h_ctx for one t, emitted as bf16 hi/lo -------
__global__ __launch_bounds__(256) void hctx_t_k(const unsigned short* __restrict__ H3h,
                                                const unsigned short* __restrict__ H3l,
                                                const float* __restrict__ beta,
                                                unsigned short* __restrict__ hcth,
                                                unsigned short* __restrict__ hctl,
                                                int t)
{
    int b = blockIdx.x, tid = threadIdx.x;
    __shared__ float Hs[16][513];
    __shared__ float bs[16];
    for (int i = tid; i < 16 * 512; i += 256) {
        int s = i >> 9, h = i & 511;
        size_t o = ((size_t)s * Bb + b) * Hh + h;
        Hs[s][h] = bf2f(H3h[o]) + bf2f(H3l[o]);
    }
    if (tid < 16) bs[tid] = beta[((size_t)t * Bb + b) * 16 + tid];
    __syncthreads();
    for (int h = tid; h < Hh; h += 256) {
        float acc = 0.0f;
#pragma unroll
        for (int s = 0; s < 16; s++) acc = fmaf(bs[s], Hs[s][h], acc);
        unsigned short hb = f2bf(acc);
        hcth[(size_t)b * Hh + h] = hb;
        hctl[(size_t)b * Hh + h] = f2bf(acc - bf2f(hb));
    }
}

// ---------------- y = lh @ fc_W.T + fc_b ----------------
__global__ __launch_bounds__(256) void y_k(const float* __restrict__ lh,
                                           const float* __restrict__ fcW,
                                           const float* __restrict__ fcb,
                                           float* __restrict__ yv,
                                           float* __restrict__ outp)
{
    int b = blockIdx.x, tid = threadIdx.x;
    __shared__ float red[256];
    float p = lh[(size_t)b * Hh + tid] * fcW[tid]
            + lh[(size_t)b * Hh + 256 + tid] * fcW[256 + tid];
    red[tid] = p; __syncthreads();
    for (int s = 128; s > 0; s >>= 1) {
        if (tid < s) red[tid] += red[tid + s];
        __syncthreads();
    }
    if (tid == 0) {
        float y = red[0] + fcb[0];
        yv[b] = y;
        if (outp) outp[b] = y;
    }
}

extern "C" void kernel_launch(void* const* d_in, const int* in_sizes, int n_in,
                              void* d_out, int out_size, void* d_ws, size_t ws_size,
                              hipStream_t stream)
{
    (void)in_sizes; (void)n_in; (void)out_size; (void)ws_size;
    const float* X     = (const float*)d_in[0];
    const float* sa_W  = (const float*)d_in[1];
    const float* sa_U  = (const float*)d_in[2];
    const float* sa_b  = (const float*)d_in[3];
    const float* sa_Wa = (const float*)d_in[4];
    const float* sa_Ua = (const float*)d_in[5];
    const float* sa_ba = (const float*)d_in[6];
    const float* sa_Va = (const float*)d_in[7];
    const float* ta_Wa = (const float*)d_in[8];
    // d_in[9] = ta_Ua : multiplied by s0 == 0 -> unused
    const float* ta_ba = (const float*)d_in[10];
    const float* ta_Va = (const float*)d_in[11];
    const float* ta_W  = (const float*)d_in[12];
    const float* ta_U  = (const float*)d_in[13];
    const float* ta_b  = (const float*)d_in[14];
    const float* ta_Wy = (const float*)d_in[15];
    const float* fc_W  = (const float*)d_in[16];
    const float* fc_b  = (const float*)d_in[17];

    char* base = (char*)d_ws;
    size_t off = 0;
    auto alloc = [&](size_t bytes) {
        void* p = base + off; off += (bytes + 255) & ~(size_t)255; return p;
    };
    const size_t BH = (size_t)Bb * Hh;          // 2M elems
    float* gates = (float*)alloc(BH * 4 * 4);   // 32 MiB (hosts avxt window)
    float* avxt  = gates;                        // 4 MiB fp32 window (dead before gates write)
    unsigned short* H3h = (unsigned short*)alloc((size_t)Ss * BH * 2);  // 64 MiB
    unsigned short* H3l = (unsigned short*)alloc((size_t)Ss * BH * 2);  // 64 MiB
    float* cbuf = (float*)alloc(BH * 4);         // 8 MiB (sa c fp32; ta: lhh/lhl alias)
    float* lh   = (float*)alloc(BH * 4);         // 8 MiB
    float* lc   = (float*)alloc(BH * 4);         // 8 MiB
    unsigned short* xth = (unsigned short*)alloc((size_t)Bb * Dd * 2);  // 2 MiB
    unsigned short* xtl = (unsigned short*)alloc((size_t)Bb * Dd * 2);  // 2 MiB
    unsigned short* xsh = (unsigned short*)alloc((size_t)Bb * Dd * 2);  // 2 MiB
    unsigned short* xsl = (unsigned short*)alloc((size_t)Bb * Dd * 2);  // 2 MiB
    unsigned short* ch  = (unsigned short*)alloc(BH * 2);               // 4 MiB
    unsigned short* cl  = (unsigned short*)alloc(BH * 2);               // 4 MiB
    unsigned short* tmph = (unsigned short*)alloc((size_t)Bb * Dd * 2); // 2 MiB
    unsigned short* tmpl = (unsigned short*)alloc((size_t)Bb * Dd * 2); // 2 MiB
    unsigned short* saWth = (unsigned short*)alloc((size_t)Dd * 4 * Hh * 2);
    unsigned short* saWtl = (unsigned short*)alloc((size_t)Dd * 4 * Hh * 2);
    unsigned short* saUth = (unsigned short*)alloc((size_t)Hh * 4 * Hh * 2);
    unsigned short* saUtl = (unsigned short*)alloc((size_t)Hh * 4 * Hh * 2);
    unsigned short* taWth = (unsigned short*)alloc((size_t)Hh * 4 * Hh * 2);
    unsigned short* taWtl = (unsigned short*)alloc((size_t)Hh * 4 * Hh * 2);
    unsigned short* taUth = (unsigned short*)alloc((size_t)Hh * 4 * Hh * 2);
    unsigned short* taUtl = (unsigned short*)alloc((size_t)Hh * 4 * Hh * 2);
    unsigned short* WaTh = (unsigned short*)alloc((size_t)Dd * Dd * 2);
    unsigned short* WaTl = (unsigned short*)alloc((size_t)Dd * Dd * 2);
    unsigned short* UaTh = (unsigned short*)alloc((size_t)2 * Hh * Dd * 2);
    unsigned short* UaTl = (unsigned short*)alloc((size_t)2 * Hh * Dd * 2);
    unsigned short* VaTh = (unsigned short*)alloc((size_t)Dd * Dd * 2);
    unsigned short* VaTl = (unsigned short*)alloc((size_t)Dd * Dd * 2);
    float* yv = (float*)alloc((size_t)Bb * 4);
    // aliases (dead at time of reuse):
    float* beta = (float*)xth;                   // 4 MiB over xth+xtl (ta phase)
    unsigned short* hcth = ch;                   // ta phase (ch/cl dead)
    unsigned short* hctl = cl;
    unsigned short* lhh = (unsigned short*)cbuf; // ta phase (cbuf dead)
    unsigned short* lhl = (unsigned short*)cbuf + BH;
    // total ~219.5 MiB

    // ---- weight prep: split + transpose to [N][K] bf16 hi/lo ----
    splitT_k<<<dim3(Dd / 32, (4 * Hh) / 32), 256, 0, stream>>>(sa_W, saWth, saWtl, Dd, 4 * Hh);
    splitT_k<<<dim3(Hh / 32, (4 * Hh) / 32), 256, 0, stream>>>(sa_U, saUth, saUtl, Hh, 4 * Hh);
    splitT_k<<<dim3(Hh / 32, (4 * Hh) / 32), 256, 0, stream>>>(ta_W, taWth, taWtl, Hh, 4 * Hh);
    splitT_k<<<dim3(Hh / 32, (4 * Hh) / 32), 256, 0, stream>>>(ta_U, taUth, taUtl, Hh, 4 * Hh);
    splitT_k<<<dim3(Dd / 32, Dd / 32), 256, 0, stream>>>(sa_Wa, WaTh, WaTl, Dd, Dd);
    splitT_k<<<dim3((2 * Hh) / 32, Dd / 32), 256, 0, stream>>>(sa_Ua, UaTh, UaTl, 2 * Hh, Dd);
    splitT_k<<<dim3(Dd / 32, Dd / 32), 256, 0, stream>>>(sa_Va, VaTh, VaTl, Dd, Dd);
    init_k<<<dim3((Bb * Dd) / 256), 256, 0, stream>>>(X, xsh, xsl, yv);

    const dim3 agrid(Bb / 64, Dd / 64);            // 64 x 4
    const dim3 ggrid(Bb / 128, (4 * Hh) / 128);    // 32 x 16

    // ---- spatial-attention LSTM ----
    for (int t = 0; t < Ss; ++t) {
        // tmp = tanh(x_t @ sa_Wa + h @ Ua[:HS] + c @ Ua[HS:] + sa_ba) [MFMA]
        SegB a0{ xsh, xsl, WaTh, WaTl, Dd, Dd, Dd };
        if (t == 0) {
            gemm_mfma_k<64, 64, 1, 1><<<agrid, 256, 0, stream>>>(
                a0, a0, a0, sa_ba, nullptr, tmph, tmpl, Dd);
        } else {
            SegB a1{ H3h + (size_t)(t - 1) * BH, H3l + (size_t)(t - 1) * BH,
                     UaTh, UaTl, Hh, 2 * Hh, Hh };
            SegB a2{ ch, cl, UaTh + Hh, UaTl + Hh, Hh, 2 * Hh, Hh };
            gemm_mfma_k<64, 64, 3, 1><<<agrid, 256, 0, stream>>>(
                a0, a1, a2, sa_ba, nullptr, tmph, tmpl, Dd);
        }

        // av = tmp @ sa_Va  [MFMA]
        SegB v0{ tmph, tmpl, VaTh, VaTl, Dd, Dd, Dd };
        gemm_mfma_k<64, 64, 1, 0><<<agrid, 256, 0, stream>>>(
            v0, v0, v0, nullptr, avxt, nullptr, nullptr, Dd);

        softmax_xt_k<<<Bb, 256, 0, stream>>>(avxt, X, xth, xtl, t);

        // gates = xt @ sa_W (+ h @ sa_U)  [MFMA]
        SegB g0{ xth, xtl, saWth, saWtl, Dd, Dd, Dd };
        if (t == 0) {
            gemm_mfma_k<128, 128, 1, 0><<<ggrid, 256, 0, stream>>>(
                g0, g0, g0, nullptr, gates, nullptr, nullptr, 4 * Hh);
            lstm_sa_k<1, 1><<<(int)(BH / 256), 256, 0, stream>>>(
                gates, sa_b, cbuf, H3h + (size_t)t * BH, H3l + (size_t)t * BH,
                ch, cl, X, xsh, xsl, t + 1);
        } else {
            SegB g1{ H3h + (size_t)(t - 1) * BH, H3l + (size_t)(t - 1) * BH,
                     saUth, saUtl, Hh, Hh, Hh };
            gemm_mfma_k<128, 128, 2, 0><<<ggrid, 256, 0, stream>>>(
                g0, g1, g1, nullptr, gates, nullptr, nullptr, 4 * Hh);
            if (t < Ss - 1)
                lstm_sa_k<0, 1><<<(int)(BH / 256), 256, 0, stream>>>(
                    gates, sa_b, cbuf, H3h + (size_t)t * BH, H3l + (size_t)t * BH,
                    ch, cl, X, xsh, xsl, t + 1);
            else
                lstm_sa_k<0, 0><<<(int)(BH / 256), 256, 0, stream>>>(
                    gates, sa_b, cbuf, H3h + (size_t)t * BH, H3l + (size_t)t * BH,
                    ch, cl, X, xsh, xsl, 0);
        }
    }

    // ---- temporal attention weights (all steps; s0 == 0) ----
    beta_k<<<dim3(Bb / 16, Ss), 256, 0, stream>>>(H3h, H3l, ta_Wa, ta_ba, ta_Va, beta);

    // ---- temporal LSTM ----
    for (int t = 0; t < Ss; ++t) {
        hctx_t_k<<<Bb, 256, 0, stream>>>(H3h, H3l, beta, hcth, hctl, t);

        // gates = h_ctx_t @ ta_W (+ lh @ ta_U)  [MFMA]
        SegB g0{ hcth, hctl, taWth, taWtl, Hh, Hh, Hh };
        if (t == 0) {
            gemm_mfma_k<128, 128, 1, 0><<<ggrid, 256, 0, stream>>>(
                g0, g0, g0, nullptr, gates, nullptr, nullptr, 4 * Hh);
            lstm_ta_k<1><<<(int)(BH / 256), 256, 0, stream>>>(
                gates, ta_b, ta_Wy, yv, lc, lh, lhh, lhl);
        } else {
            SegB g1{ lhh, lhl, taUth, taUtl, Hh, Hh, Hh };
            gemm_mfma_k<128, 128, 2, 0><<<ggrid, 256, 0, stream>>>(
                g0, g1, g1, nullptr, gates, nullptr, nullptr, 4 * Hh);
            lstm_ta_k<0><<<(int)(BH / 256), 256, 0, stream>>>(
                gates, ta_b, ta_Wy, yv, lc, lh, lhh, lhl);
        }

        y_k<<<Bb, 256, 0, stream>>>(lh, fc_W, fc_b, yv,
                                    (t == Ss - 1) ? (float*)d_out : nullptr);
    }
}

// Round 5
// 2915.732 us; speedup vs baseline: 2.7394x; 1.1077x over previous
//
#include <hip/hip_runtime.h>

// STA-LSTM forward. B=4096 S=16 D=256 HS=HT=512. Output y (B,1) fp32.
// R5 (on top of R4's all-MFMA structure):
//   - hctx_all_k: ONE dispatch computes h_ctx for all 16 t, overwriting H3
//     planes in place (block touches only its own batch row -> race-free).
//     Kills 16x full re-read of H3 (2.3 GB -> 256 MiB).
//   - beta_k: K-split across 16 threads/row (16 accs each + LDS reduce),
//     ~4x less VALU than the per-n-redundant loop.
//   - lstm_ta_k: 512-thr blocks, fused y = lh@fcW+fcb reduction (y_k gone).
// ws: ~203.5 MiB.

constexpr int Bb = 4096;
constexpr int Ss = 16;
constexpr int Dd = 256;
constexpr int Hh = 512;   // HS == HT

typedef __attribute__((ext_vector_type(8))) short short8;
typedef __attribute__((ext_vector_type(4))) float f32x4;

__device__ __forceinline__ float sigm(float x) { return 1.0f / (1.0f + expf(-x)); }

__device__ __forceinline__ unsigned short f2bf(float x) {   // RNE fp32->bf16 bits
    unsigned int u = __float_as_uint(x);
    u = (u + 0x7fffu + ((u >> 16) & 1u)) >> 16;
    return (unsigned short)u;
}
__device__ __forceinline__ float bf2f(unsigned short h) {
    return __uint_as_float(((unsigned int)h) << 16);
}
__device__ __forceinline__ void async16(const void* g, void* l) {
    __builtin_amdgcn_global_load_lds(
        (const __attribute__((address_space(1))) void*)g,
        (__attribute__((address_space(3))) void*)l, 16, 0, 0);
}

// ================= split-bf16 MFMA GEMM (generic) =================
// C[M,N] = sum_seg (Ah+Al)[M,K] @ (Bh+Bl)[N,K]^T, dropping Al*Bl.
// EPI=0: store fp32 C. EPI=1: v=tanh(acc+bias[col]); split-store to Th/Tl.
struct SegB { const unsigned short* Ah; const unsigned short* Al;
              const unsigned short* Bh; const unsigned short* Bl;
              int lda; int ldb; int K; };

template<int BM, int BN, int NSEG, int EPI>
__global__ __launch_bounds__(256) void gemm_mfma_k(
    SegB s0, SegB s1, SegB s2,
    const float* __restrict__ bias,
    float* __restrict__ C,
    unsigned short* __restrict__ Th, unsigned short* __restrict__ Tl,
    int ldc)
{
    constexpr int WM = BM / 2, WN = BN / 2;
    constexpr int FI = WM / 16, FJ = WN / 16;
    __shared__ __align__(16) unsigned short sA[2][BM * 32];  // [hi/lo][m][k]
    __shared__ __align__(16) unsigned short sB[2][BN * 32];  // [hi/lo][n][k]
    const int tid  = threadIdx.x;
    const int lane = tid & 63;
    const int wv   = tid >> 6;          // 4 waves, 2x2
    const int wm   = wv & 1, wn = wv >> 1;
    const int row0 = blockIdx.x * BM;
    const int col0 = blockIdx.y * BN;

    f32x4 acc[FI][FJ];
#pragma unroll
    for (int i = 0; i < FI; i++)
#pragma unroll
        for (int j = 0; j < FJ; j++) acc[i][j] = (f32x4){0.f, 0.f, 0.f, 0.f};

    const int lrow = lane >> 2;          // 0..15 row within 16-row chunk
    const int lcol = (lane & 3) * 8;     // element offset within 32-elem row
    const int q8   = (lane >> 4) * 8;    // frag k-offset
    const int l15  = lane & 15;

#pragma unroll
    for (int sgi = 0; sgi < NSEG; ++sgi) {
        const SegB sg = (sgi == 0) ? s0 : ((sgi == 1) ? s1 : s2);
        const int K = sg.K;
        for (int k0 = 0; k0 < K; k0 += 32) {
            // ---- stage tiles via global_load_lds (16B chunks) ----
#pragma unroll
            for (int c = wv; c < BM / 16; c += 4) {
                const int r = c * 16 + lrow;
                const size_t gA = (size_t)(row0 + r) * sg.lda + k0 + lcol;
                const int lo = c * 512 + lane * 8;
                async16(sg.Ah + gA, &sA[0][lo]);
                async16(sg.Al + gA, &sA[1][lo]);
            }
#pragma unroll
            for (int c = wv; c < BN / 16; c += 4) {
                const int r = c * 16 + lrow;
                const size_t gB = (size_t)(col0 + r) * sg.ldb + k0 + lcol;
                const int lo = c * 512 + lane * 8;
                async16(sg.Bh + gB, &sB[0][lo]);
                async16(sg.Bl + gB, &sB[1][lo]);
            }
            __syncthreads();
            // ---- fragments ----
            short8 ah[FI], al[FI], bh[FJ], bl[FJ];
#pragma unroll
            for (int i = 0; i < FI; i++) {
                const int m = wm * WM + i * 16 + l15;
                ah[i] = *reinterpret_cast<const short8*>(&sA[0][m * 32 + q8]);
                al[i] = *reinterpret_cast<const short8*>(&sA[1][m * 32 + q8]);
            }
#pragma unroll
            for (int j = 0; j < FJ; j++) {
                const int n = wn * WN + j * 16 + l15;
                bh[j] = *reinterpret_cast<const short8*>(&sB[0][n * 32 + q8]);
                bl[j] = *reinterpret_cast<const short8*>(&sB[1][n * 32 + q8]);
            }
#pragma unroll
            for (int i = 0; i < FI; i++)
#pragma unroll
                for (int j = 0; j < FJ; j++) {
                    acc[i][j] = __builtin_amdgcn_mfma_f32_16x16x32_bf16(ah[i], bh[j], acc[i][j], 0, 0, 0);
                    acc[i][j] = __builtin_amdgcn_mfma_f32_16x16x32_bf16(ah[i], bl[j], acc[i][j], 0, 0, 0);
                    acc[i][j] = __builtin_amdgcn_mfma_f32_16x16x32_bf16(al[i], bh[j], acc[i][j], 0, 0, 0);
                }
            __syncthreads();
        }
    }
    // ---- epilogue: C/D layout col=lane&15, row=(lane>>4)*4+r ----
#pragma unroll
    for (int i = 0; i < FI; i++) {
#pragma unroll
        for (int j = 0; j < FJ; j++) {
            const int col = col0 + wn * WN + j * 16 + l15;
#pragma unroll
            for (int r = 0; r < 4; r++) {
                const int row = row0 + wm * WM + i * 16 + (lane >> 4) * 4 + r;
                float v = acc[i][j][r];
                if (EPI == 1) {
                    v = tanhf(v + bias[col]);
                    unsigned short hb = f2bf(v);
                    Th[(size_t)row * ldc + col] = hb;
                    Tl[(size_t)row * ldc + col] = f2bf(v - bf2f(hb));
                } else {
                    C[(size_t)row * ldc + col] = v;
                }
            }
        }
    }
}

// ============ weight prep: W[K][N] fp32 -> Th,Tl [N][K] bf16 ============
__global__ __launch_bounds__(256) void splitT_k(const float* __restrict__ W,
                                                unsigned short* __restrict__ Th,
                                                unsigned short* __restrict__ Tl,
                                                int Kd, int Nd)
{
    __shared__ float tile[32][33];
    const int bk = blockIdx.x * 32, bn = blockIdx.y * 32;
    const int tid = threadIdx.x;
    const int r = tid >> 3, c4 = (tid & 7) * 4;
    const float4 v = *reinterpret_cast<const float4*>(&W[(size_t)(bk + r) * Nd + bn + c4]);
    tile[r][c4 + 0] = v.x; tile[r][c4 + 1] = v.y;
    tile[r][c4 + 2] = v.z; tile[r][c4 + 3] = v.w;
    __syncthreads();
    const int n = r, k4 = c4;
    ushort4 hq, lq;
    unsigned short* hp = (unsigned short*)&hq;
    unsigned short* lp = (unsigned short*)&lq;
#pragma unroll
    for (int q = 0; q < 4; q++) {
        float x = tile[k4 + q][n];
        unsigned short h = f2bf(x);
        hp[q] = h;
        lp[q] = f2bf(x - bf2f(h));
    }
    *reinterpret_cast<ushort4*>(&Th[(size_t)(bn + n) * Kd + bk + k4]) = hq;
    *reinterpret_cast<ushort4*>(&Tl[(size_t)(bn + n) * Kd + bk + k4]) = lq;
}

// -------- init: y0 = X[:,0,255]; split X[:,0,:] to xsh/xsl --------
__global__ __launch_bounds__(256) void init_k(const float* __restrict__ X,
                                              unsigned short* __restrict__ xsh,
                                              unsigned short* __restrict__ xsl,
                                              float* __restrict__ yv)
{
    int idx = blockIdx.x * 256 + threadIdx.x;   // over Bb*Dd
    int b = idx >> 8, d = idx & 255;
    float xv = X[(size_t)b * (Ss * Dd) + d];    // t = 0
    unsigned short hb = f2bf(xv);
    xsh[idx] = hb;
    xsl[idx] = f2bf(xv - bf2f(hb));
    if (d == Dd - 1) yv[b] = xv;
}

// ------- softmax over D, scale by x_t, emit bf16 hi/lo xt -------
__global__ __launch_bounds__(256) void softmax_xt_k(const float* __restrict__ a,
                                                    const float* __restrict__ X,
                                                    unsigned short* __restrict__ xh,
                                                    unsigned short* __restrict__ xl,
                                                    int t)
{
    int b = blockIdx.x, tid = threadIdx.x;
    __shared__ float red[256];
    float v = a[(size_t)b * Dd + tid];
    red[tid] = v; __syncthreads();
    for (int s = 128; s > 0; s >>= 1) {
        if (tid < s) red[tid] = fmaxf(red[tid], red[tid + s]);
        __syncthreads();
    }
    float mx = red[0]; __syncthreads();
    float e = expf(v - mx);
    red[tid] = e; __syncthreads();
    for (int s = 128; s > 0; s >>= 1) {
        if (tid < s) red[tid] += red[tid + s];
        __syncthreads();
    }
    float inv = 1.0f / red[0];
    float xv = e * inv * X[(size_t)b * Ss * Dd + (size_t)t * Dd + tid];
    unsigned short h = f2bf(xv);
    xh[(size_t)b * Dd + tid] = h;
    xl[(size_t)b * Dd + tid] = f2bf(xv - bf2f(h));
}

// ------- sa LSTM pointwise: c fp32 in-place + bf16 h/c hi/lo;
//         optionally piggyback the split of X[:,tnext,:] -------
template<int ZC, int SPLITX>
__global__ __launch_bounds__(256) void lstm_sa_k(
    const float* __restrict__ gates, const float* __restrict__ bias,
    float* __restrict__ c_io,
    unsigned short* __restrict__ h3h, unsigned short* __restrict__ h3l,
    unsigned short* __restrict__ ch, unsigned short* __restrict__ cl,
    const float* __restrict__ X,
    unsigned short* __restrict__ xsh, unsigned short* __restrict__ xsl,
    int tnext)
{
    int idx = blockIdx.x * 256 + threadIdx.x;   // Bb*Hh
    int b = idx >> 9, j = idx & 511;
    const float* g = gates + (size_t)b * 4 * Hh;
    float gi = g[j]          + bias[j];
    float gf = g[Hh + j]     + bias[Hh + j];
    float gg = g[2 * Hh + j] + bias[2 * Hh + j];
    float go = g[3 * Hh + j] + bias[3 * Hh + j];
    float i_ = sigm(gi), f_ = sigm(gf), gv = tanhf(gg), o_ = sigm(go);
    float cp = ZC ? 0.0f : c_io[idx];
    float c = f_ * cp + i_ * gv;
    c_io[idx] = c;
    unsigned short cb = f2bf(c);
    ch[idx] = cb;
    cl[idx] = f2bf(c - bf2f(cb));
    float h = o_ * tanhf(c);
    unsigned short hb = f2bf(h);
    h3h[idx] = hb;
    h3l[idx] = f2bf(h - bf2f(hb));
    if (SPLITX && j < Dd) {
        float xv = X[(size_t)b * (Ss * Dd) + (size_t)tnext * Dd + j];
        unsigned short xb = f2bf(xv);
        xsh[(size_t)b * Dd + j] = xb;
        xsl[(size_t)b * Dd + j] = f2bf(xv - bf2f(xb));
    }
}

// ------- ta LSTM pointwise, 512-thr blocks, fused y reduction -------
template<int ZC>
__global__ __launch_bounds__(512) void lstm_ta_k(const float* __restrict__ gates,
                                                 const float* __restrict__ bias,
                                                 const float* __restrict__ wy,
                                                 const float* __restrict__ fcW,
                                                 const float* __restrict__ fcb,
                                                 float* __restrict__ yv,
                                                 float* __restrict__ c_io,
                                                 unsigned short* __restrict__ hh,
                                                 unsigned short* __restrict__ hl,
                                                 float* __restrict__ outp)
{
    int b = blockIdx.x, j = threadIdx.x;        // j = 0..511
    size_t idx = (size_t)b * Hh + j;
    const float* g = gates + (size_t)b * 4 * Hh;
    float yb = yv[b];                            // read BEFORE barrier
    float gi = g[j]          + bias[j]          + yb * wy[j];
    float gf = g[Hh + j]     + bias[Hh + j]     + yb * wy[Hh + j];
    float gg = g[2 * Hh + j] + bias[2 * Hh + j] + yb * wy[2 * Hh + j];
    float go = g[3 * Hh + j] + bias[3 * Hh + j] + yb * wy[3 * Hh + j];
    float i_ = sigm(gi), f_ = sigm(gf), gv = tanhf(gg), o_ = sigm(go);
    float cp = ZC ? 0.0f : c_io[idx];
    float c = f_ * cp + i_ * gv;
    c_io[idx] = c;
    float h = o_ * tanhf(c);
    unsigned short hb = f2bf(h);
    hh[idx] = hb;
    hl[idx] = f2bf(h - bf2f(hb));
    // ---- y = sum_j h*fcW[j] + fcb ----
    float p = h * fcW[j];
#pragma unroll
    for (int off = 32; off > 0; off >>= 1) p += __shfl_down(p, off, 64);
    __shared__ float wred[8];
    if ((j & 63) == 0) wred[j >> 6] = p;
    __syncthreads();
    if (j == 0) {
        float y = fcb[0];
#pragma unroll
        for (int w = 0; w < 8; w++) y += wred[w];
        yv[b] = y;                               // write AFTER barrier
        if (outp) outp[b] = y;
    }
}

// ------- beta = softmax(tanh(h_t @ ta_Wa + ta_ba) @ ta_Va); s0==0 -------
// K-split: 16 threads/row, each owns K-chunk of 32 with 16 accumulators.
__global__ __launch_bounds__(256) void beta_k(const unsigned short* __restrict__ H3h,
                                              const unsigned short* __restrict__ H3l,
                                              const float* __restrict__ taWa,
                                              const float* __restrict__ taba,
                                              const float* __restrict__ taVa,
                                              float* __restrict__ beta)
{
    int bx = blockIdx.x, t = blockIdx.y, tid = threadIdx.x;
    __shared__ float Was[512 * 16];      // 32 KB
    __shared__ float red[16 * 16 * 16];  // 16 KB  [r][n][c]
    __shared__ float Vas[256];
    __shared__ float tt[16][17];
    __shared__ float lt[16][17];
    for (int i = tid; i < 512 * 16; i += 256) Was[i] = taWa[i];
    Vas[tid] = taVa[tid];
    __syncthreads();
    const int r = tid >> 4, c = tid & 15;
    const int b = bx * 16 + r;
    const unsigned short* hrh = H3h + ((size_t)t * Bb + b) * Hh + c * 32;
    const unsigned short* hrl = H3l + ((size_t)t * Bb + b) * Hh + c * 32;
    float acc[16];
#pragma unroll
    for (int n = 0; n < 16; n++) acc[n] = 0.0f;
    for (int k = 0; k < 32; k++) {
        float hk = bf2f(hrh[k]) + bf2f(hrl[k]);
        const float* w = &Was[(c * 32 + k) * 16];
#pragma unroll
        for (int n = 0; n < 16; n++) acc[n] = fmaf(hk, w[n], acc[n]);
    }
#pragma unroll
    for (int n = 0; n < 16; n++) red[(r * 16 + n) * 16 + c] = acc[n];
    __syncthreads();
    // thread (r, n=c) reduces its logit over the 16 chunks
    float s = 0.0f;
#pragma unroll
    for (int cc = 0; cc < 16; cc++) s += red[(r * 16 + c) * 16 + cc];
    tt[r][c] = tanhf(s + taba[c]);
    __syncthreads();
    float l = 0.0f;
#pragma unroll
    for (int m = 0; m < 16; m++) l = fmaf(tt[r][m], Vas[m * 16 + c], l);
    lt[r][c] = l;
    __syncthreads();
    float mx = -1e30f;
#pragma unroll
    for (int m = 0; m < 16; m++) mx = fmaxf(mx, lt[r][m]);
    float sum = 0.0f;
#pragma unroll
    for (int m = 0; m < 16; m++) sum += expf(lt[r][m] - mx);
    beta[((size_t)t * Bb + b) * 16 + c] = expf(l - mx) / sum;
}

// ------- h_ctx for ALL t in one dispatch, in-place into H3 -------
// Block b reads all H3[s][b][:] into LDS first, then overwrites plane t
// with HC[t][b][:]. Writes touch only batch row b -> no cross-block race.
__global__ __launch_bounds__(256) void hctx_all_k(unsigned short* __restrict__ H3h,
                                                  unsigned short* __restrict__ H3l,
                                                  const float* __restrict__ beta)
{
    int b = blockIdx.x, tid = threadIdx.x;
    __shared__ float Hs[16][516];
    __shared__ float bs[16][16];
    for (int i = tid; i < 16 * 512; i += 256) {
        int s = i >> 9, h = i & 511;
        size_t o = ((size_t)s * Bb + b) * Hh + h;
        Hs[s][h] = bf2f(H3h[o]) + bf2f(H3l[o]);
    }
    {
        int t = tid >> 4, s = tid & 15;
        bs[t][s] = beta[((size_t)t * Bb + b) * 16 + s];
    }
    __syncthreads();
#pragma unroll
    for (int t = 0; t < 16; t++) {
        for (int h = tid; h < Hh; h += 256) {
            float a = 0.0f;
#pragma unroll
            for (int s = 0; s < 16; s++) a = fmaf(bs[t][s], Hs[s][h], a);
            unsigned short hb = f2bf(a);
            size_t o = ((size_t)t * Bb + b) * Hh + h;
            H3h[o] = hb;
            H3l[o] = f2bf(a - bf2f(hb));
        }
    }
}

extern "C" void kernel_launch(void* const* d_in, const int* in_sizes, int n_in,
                              void* d_out, int out_size, void* d_ws, size_t ws_size,
                              hipStream_t stream)
{
    (void)in_sizes; (void)n_in; (void)out_size; (void)ws_size;
    const float* X     = (const float*)d_in[0];
    const float* sa_W  = (const float*)d_in[1];
    const float* sa_U  = (const float*)d_in[2];
    const float* sa_b  = (const float*)d_in[3];
    const float* sa_Wa = (const float*)d_in[4];
    const float* sa_Ua = (const float*)d_in[5];
    const float* sa_ba = (const float*)d_in[6];
    const float* sa_Va = (const float*)d_in[7];
    const float* ta_Wa = (const float*)d_in[8];
    // d_in[9] = ta_Ua : multiplied by s0 == 0 -> unused
    const float* ta_ba = (const float*)d_in[10];
    const float* ta_Va = (const float*)d_in[11];
    const float* ta_W  = (const float*)d_in[12];
    const float* ta_U  = (const float*)d_in[13];
    const float* ta_b  = (const float*)d_in[14];
    const float* ta_Wy = (const float*)d_in[15];
    const float* fc_W  = (const float*)d_in[16];
    const float* fc_b  = (const float*)d_in[17];

    char* base = (char*)d_ws;
    size_t off = 0;
    auto alloc = [&](size_t bytes) {
        void* p = base + off; off += (bytes + 255) & ~(size_t)255; return p;
    };
    const size_t BH = (size_t)Bb * Hh;          // 2M elems
    float* gates = (float*)alloc(BH * 4 * 4);   // 32 MiB (hosts avxt window)
    float* avxt  = gates;                        // 4 MiB fp32 window
    unsigned short* H3h = (unsigned short*)alloc((size_t)Ss * BH * 2);  // 64 MiB
    unsigned short* H3l = (unsigned short*)alloc((size_t)Ss * BH * 2);  // 64 MiB
    float* cbuf = (float*)alloc(BH * 4);         // 8 MiB (sa c fp32; ta: lhh/lhl alias)
    float* lc   = (float*)alloc(BH * 4);         // 8 MiB
    unsigned short* xth = (unsigned short*)alloc((size_t)Bb * Dd * 2);  // 2 MiB
    unsigned short* xtl = (unsigned short*)alloc((size_t)Bb * Dd * 2);  // 2 MiB
    unsigned short* xsh = (unsigned short*)alloc((size_t)Bb * Dd * 2);  // 2 MiB
    unsigned short* xsl = (unsigned short*)alloc((size_t)Bb * Dd * 2);  // 2 MiB
    unsigned short* ch  = (unsigned short*)alloc(BH * 2);               // 4 MiB
    unsigned short* cl  = (unsigned short*)alloc(BH * 2);               // 4 MiB
    unsigned short* tmph = (unsigned short*)alloc((size_t)Bb * Dd * 2); // 2 MiB
    unsigned short* tmpl = (unsigned short*)alloc((size_t)Bb * Dd * 2); // 2 MiB
    unsigned short* saWth = (unsigned short*)alloc((size_t)Dd * 4 * Hh * 2);
    unsigned short* saWtl = (unsigned short*)alloc((size_t)Dd * 4 * Hh * 2);
    unsigned short* saUth = (unsigned short*)alloc((size_t)Hh * 4 * Hh * 2);
    unsigned short* saUtl = (unsigned short*)alloc((size_t)Hh * 4 * Hh * 2);
    unsigned short* taWth = (unsigned short*)alloc((size_t)Hh * 4 * Hh * 2);
    unsigned short* taWtl = (unsigned short*)alloc((size_t)Hh * 4 * Hh * 2);
    unsigned short* taUth = (unsigned short*)alloc((size_t)Hh * 4 * Hh * 2);
    unsigned short* taUtl = (unsigned short*)alloc((size_t)Hh * 4 * Hh * 2);
    unsigned short* WaTh = (unsigned short*)alloc((size_t)Dd * Dd * 2);
    unsigned short* WaTl = (unsigned short*)alloc((size_t)Dd * Dd * 2);
    unsigned short* UaTh = (unsigned short*)alloc((size_t)2 * Hh * Dd * 2);
    unsigned short* UaTl = (unsigned short*)alloc((size_t)2 * Hh * Dd * 2);
    unsigned short* VaTh = (unsigned short*)alloc((size_t)Dd * Dd * 2);
    unsigned short* VaTl = (unsigned short*)alloc((size_t)Dd * Dd * 2);
    float* yv = (float*)alloc((size_t)Bb * 4);
    // aliases (dead at time of reuse):
    float* beta = (float*)xth;                   // 4 MiB over xth+xtl (ta phase)
    unsigned short* lhh = (unsigned short*)cbuf; // ta phase (cbuf dead)
    unsigned short* lhl = (unsigned short*)cbuf + BH;
    // total ~203.5 MiB

    // ---- weight prep: split + transpose to [N][K] bf16 hi/lo ----
    splitT_k<<<dim3(Dd / 32, (4 * Hh) / 32), 256, 0, stream>>>(sa_W, saWth, saWtl, Dd, 4 * Hh);
    splitT_k<<<dim3(Hh / 32, (4 * Hh) / 32), 256, 0, stream>>>(sa_U, saUth, saUtl, Hh, 4 * Hh);
    splitT_k<<<dim3(Hh / 32, (4 * Hh) / 32), 256, 0, stream>>>(ta_W, taWth, taWtl, Hh, 4 * Hh);
    splitT_k<<<dim3(Hh / 32, (4 * Hh) / 32), 256, 0, stream>>>(ta_U, taUth, taUtl, Hh, 4 * Hh);
    splitT_k<<<dim3(Dd / 32, Dd / 32), 256, 0, stream>>>(sa_Wa, WaTh, WaTl, Dd, Dd);
    splitT_k<<<dim3((2 * Hh) / 32, Dd / 32), 256, 0, stream>>>(sa_Ua, UaTh, UaTl, 2 * Hh, Dd);
    splitT_k<<<dim3(Dd / 32, Dd / 32), 256, 0, stream>>>(sa_Va, VaTh, VaTl, Dd, Dd);
    init_k<<<dim3((Bb * Dd) / 256), 256, 0, stream>>>(X, xsh, xsl, yv);

    const dim3 agrid(Bb / 64, Dd / 64);            // 64 x 4
    const dim3 ggrid(Bb / 128, (4 * Hh) / 128);    // 32 x 16

    // ---- spatial-attention LSTM ----
    for (int t = 0; t < Ss; ++t) {
        // tmp = tanh(x_t @ sa_Wa + h @ Ua[:HS] + c @ Ua[HS:] + sa_ba) [MFMA]
        SegB a0{ xsh, xsl, WaTh, WaTl, Dd, Dd, Dd };
        if (t == 0) {
            gemm_mfma_k<64, 64, 1, 1><<<agrid, 256, 0, stream>>>(
                a0, a0, a0, sa_ba, nullptr, tmph, tmpl, Dd);
        } else {
            SegB a1{ H3h + (size_t)(t - 1) * BH, H3l + (size_t)(t - 1) * BH,
                     UaTh, UaTl, Hh, 2 * Hh, Hh };
            SegB a2{ ch, cl, UaTh + Hh, UaTl + Hh, Hh, 2 * Hh, Hh };
            gemm_mfma_k<64, 64, 3, 1><<<agrid, 256, 0, stream>>>(
                a0, a1, a2, sa_ba, nullptr, tmph, tmpl, Dd);
        }

        // av = tmp @ sa_Va  [MFMA]
        SegB v0{ tmph, tmpl, VaTh, VaTl, Dd, Dd, Dd };
        gemm_mfma_k<64, 64, 1, 0><<<agrid, 256, 0, stream>>>(
            v0, v0, v0, nullptr, avxt, nullptr, nullptr, Dd);

        softmax_xt_k<<<Bb, 256, 0, stream>>>(avxt, X, xth, xtl, t);

        // gates = xt @ sa_W (+ h @ sa_U)  [MFMA]
        SegB g0{ xth, xtl, saWth, saWtl, Dd, Dd, Dd };
        if (t == 0) {
            gemm_mfma_k<128, 128, 1, 0><<<ggrid, 256, 0, stream>>>(
                g0, g0, g0, nullptr, gates, nullptr, nullptr, 4 * Hh);
            lstm_sa_k<1, 1><<<(int)(BH / 256), 256, 0, stream>>>(
                gates, sa_b, cbuf, H3h + (size_t)t * BH, H3l + (size_t)t * BH,
                ch, cl, X, xsh, xsl, t + 1);
        } else {
            SegB g1{ H3h + (size_t)(t - 1) * BH, H3l + (size_t)(t - 1) * BH,
                     saUth, saUtl, Hh, Hh, Hh };
            gemm_mfma_k<128, 128, 2, 0><<<ggrid, 256, 0, stream>>>(
                g0, g1, g1, nullptr, gates, nullptr, nullptr, 4 * Hh);
            if (t < Ss - 1)
                lstm_sa_k<0, 1><<<(int)(BH / 256), 256, 0, stream>>>(
                    gates, sa_b, cbuf, H3h + (size_t)t * BH, H3l + (size_t)t * BH,
                    ch, cl, X, xsh, xsl, t + 1);
            else
                lstm_sa_k<0, 0><<<(int)(BH / 256), 256, 0, stream>>>(
                    gates, sa_b, cbuf, H3h + (size_t)t * BH, H3l + (size_t)t * BH,
                    ch, cl, X, xsh, xsl, 0);
        }
    }

    // ---- temporal attention: beta, then ALL h_ctx in place ----
    beta_k<<<dim3(Bb / 16, Ss), 256, 0, stream>>>(H3h, H3l, ta_Wa, ta_ba, ta_Va, beta);
    hctx_all_k<<<Bb, 256, 0, stream>>>(H3h, H3l, beta);

    // ---- temporal LSTM (H3 planes now hold h_ctx) ----
    for (int t = 0; t < Ss; ++t) {
        SegB g0{ H3h + (size_t)t * BH, H3l + (size_t)t * BH,
                 taWth, taWtl, Hh, Hh, Hh };
        if (t == 0) {
            gemm_mfma_k<128, 128, 1, 0><<<ggrid, 256, 0, stream>>>(
                g0, g0, g0, nullptr, gates, nullptr, nullptr, 4 * Hh);
            lstm_ta_k<1><<<Bb, 512, 0, stream>>>(
                gates, ta_b, ta_Wy, fc_W, fc_b, yv, lc, lhh, lhl,
                (t == Ss - 1) ? (float*)d_out : nullptr);
        } else {
            SegB g1{ lhh, lhl, taUth, taUtl, Hh, Hh, Hh };
            gemm_mfma_k<128, 128, 2, 0><<<ggrid, 256, 0, stream>>>(
                g0, g1, g1, nullptr, gates, nullptr, nullptr, 4 * Hh);
            lstm_ta_k<0><<<Bb, 512, 0, stream>>>(
                gates, ta_b, ta_Wy, fc_W, fc_b, yv, lc, lhh, lhl,
                (t == Ss - 1) ? (float*)d_out : nullptr);
        }
    }
}

// Round 6
// 2492.713 us; speedup vs baseline: 3.2043x; 1.1697x over previous
//
#include <hip/hip_runtime.h>

// STA-LSTM forward. B=4096 S=16 D=256 HS=HT=512. Output y (B,1) fp32.
// R6:
//   - beta: MFMA split-bf16 logits GEMM (65536x512 @ 512x16) with fused
//     tanh/@Va/softmax epilogue. R5's K-split had 16-way LDS bank conflicts
//     (1.27e8) -- this replaces it entirely.
//   - gates GEMM + LSTM pointwise FUSED: block owns (128 rows x 32 j) with
//     all 4 gate columns staged (4 strided slices of W^T), epilogue does the
//     LSTM update in-register. gates buffer (32 MiB x 2 x 32 steps HBM) and
//     32 pointwise dispatches are gone. ta lh ping-pongs (cross-block race
//     otherwise). X-split piggyback moved to softmax; y = tiny dot kernel.
// ws: ~188 MiB.

constexpr int Bb = 4096;
constexpr int Ss = 16;
constexpr int Dd = 256;
constexpr int Hh = 512;   // HS == HT

typedef __attribute__((ext_vector_type(8))) short short8;
typedef __attribute__((ext_vector_type(4))) float f32x4;

__device__ __forceinline__ float sigm(float x) { return 1.0f / (1.0f + expf(-x)); }

__device__ __forceinline__ unsigned short f2bf(float x) {   // RNE fp32->bf16 bits
    unsigned int u = __float_as_uint(x);
    u = (u + 0x7fffu + ((u >> 16) & 1u)) >> 16;
    return (unsigned short)u;
}
__device__ __forceinline__ float bf2f(unsigned short h) {
    return __uint_as_float(((unsigned int)h) << 16);
}
__device__ __forceinline__ void async16(const void* g, void* l) {
    __builtin_amdgcn_global_load_lds(
        (const __attribute__((address_space(1))) void*)g,
        (__attribute__((address_space(3))) void*)l, 16, 0, 0);
}

struct SegB { const unsigned short* Ah; const unsigned short* Al;
              const unsigned short* Bh; const unsigned short* Bl;
              int lda; int ldb; int K; };

// ================= generic split-bf16 MFMA GEMM (attention path) ==========
// C[M,N] = sum_seg (Ah+Al)[M,K] @ (Bh+Bl)[N,K]^T, dropping Al*Bl.
// EPI=0: store fp32 C. EPI=1: v=tanh(acc+bias[col]); split-store to Th/Tl.
template<int BM, int BN, int NSEG, int EPI>
__global__ __launch_bounds__(256) void gemm_mfma_k(
    SegB s0, SegB s1, SegB s2,
    const float* __restrict__ bias,
    float* __restrict__ C,
    unsigned short* __restrict__ Th, unsigned short* __restrict__ Tl,
    int ldc)
{
    constexpr int WM = BM / 2, WN = BN / 2;
    constexpr int FI = WM / 16, FJ = WN / 16;
    __shared__ __align__(16) unsigned short sA[2][BM * 32];
    __shared__ __align__(16) unsigned short sB[2][BN * 32];
    const int tid  = threadIdx.x;
    const int lane = tid & 63;
    const int wv   = tid >> 6;
    const int wm   = wv & 1, wn = wv >> 1;
    const int row0 = blockIdx.x * BM;
    const int col0 = blockIdx.y * BN;

    f32x4 acc[FI][FJ];
#pragma unroll
    for (int i = 0; i < FI; i++)
#pragma unroll
        for (int j = 0; j < FJ; j++) acc[i][j] = (f32x4){0.f, 0.f, 0.f, 0.f};

    const int lrow = lane >> 2;
    const int lcol = (lane & 3) * 8;
    const int q8   = (lane >> 4) * 8;
    const int l15  = lane & 15;

#pragma unroll
    for (int sgi = 0; sgi < NSEG; ++sgi) {
        const SegB sg = (sgi == 0) ? s0 : ((sgi == 1) ? s1 : s2);
        const int K = sg.K;
        for (int k0 = 0; k0 < K; k0 += 32) {
#pragma unroll
            for (int c = wv; c < BM / 16; c += 4) {
                const int r = c * 16 + lrow;
                const size_t gA = (size_t)(row0 + r) * sg.lda + k0 + lcol;
                const int lo = c * 512 + lane * 8;
                async16(sg.Ah + gA, &sA[0][lo]);
                async16(sg.Al + gA, &sA[1][lo]);
            }
#pragma unroll
            for (int c = wv; c < BN / 16; c += 4) {
                const int r = c * 16 + lrow;
                const size_t gB = (size_t)(col0 + r) * sg.ldb + k0 + lcol;
                const int lo = c * 512 + lane * 8;
                async16(sg.Bh + gB, &sB[0][lo]);
                async16(sg.Bl + gB, &sB[1][lo]);
            }
            __syncthreads();
            short8 ah[FI], al[FI], bh[FJ], bl[FJ];
#pragma unroll
            for (int i = 0; i < FI; i++) {
                const int m = wm * WM + i * 16 + l15;
                ah[i] = *reinterpret_cast<const short8*>(&sA[0][m * 32 + q8]);
                al[i] = *reinterpret_cast<const short8*>(&sA[1][m * 32 + q8]);
            }
#pragma unroll
            for (int j = 0; j < FJ; j++) {
                const int n = wn * WN + j * 16 + l15;
                bh[j] = *reinterpret_cast<const short8*>(&sB[0][n * 32 + q8]);
                bl[j] = *reinterpret_cast<const short8*>(&sB[1][n * 32 + q8]);
            }
#pragma unroll
            for (int i = 0; i < FI; i++)
#pragma unroll
                for (int j = 0; j < FJ; j++) {
                    acc[i][j] = __builtin_amdgcn_mfma_f32_16x16x32_bf16(ah[i], bh[j], acc[i][j], 0, 0, 0);
                    acc[i][j] = __builtin_amdgcn_mfma_f32_16x16x32_bf16(ah[i], bl[j], acc[i][j], 0, 0, 0);
                    acc[i][j] = __builtin_amdgcn_mfma_f32_16x16x32_bf16(al[i], bh[j], acc[i][j], 0, 0, 0);
                }
            __syncthreads();
        }
    }
#pragma unroll
    for (int i = 0; i < FI; i++) {
#pragma unroll
        for (int j = 0; j < FJ; j++) {
            const int col = col0 + wn * WN + j * 16 + l15;
#pragma unroll
            for (int r = 0; r < 4; r++) {
                const int row = row0 + wm * WM + i * 16 + (lane >> 4) * 4 + r;
                float v = acc[i][j][r];
                if (EPI == 1) {
                    v = tanhf(v + bias[col]);
                    unsigned short hb = f2bf(v);
                    Th[(size_t)row * ldc + col] = hb;
                    Tl[(size_t)row * ldc + col] = f2bf(v - bf2f(hb));
                } else {
                    C[(size_t)row * ldc + col] = v;
                }
            }
        }
    }
}

// ============ fused gates GEMM + LSTM pointwise ============
// Block = (128 batch rows) x (32 j). B-tile = rows {g*512 + j0+jj} of W^T
// for g=0..3 -> each thread ends with gi/gf/gg/go for its (row,j) pairs.
// TA=0 (sa): c fp32 in-place + split c -> ch/cl, h -> hh/hl (H3 plane).
// TA=1 (ta): + y_prev*wy rank-1; c fp32 in-place (lc); h -> hh/hl (lh pong).
template<int NSEG, int ZC, int TA>
__global__ __launch_bounds__(256) void gemm_gates_k(
    SegB s0, SegB s1,
    const float* __restrict__ bias,
    const float* __restrict__ wy,
    const float* __restrict__ yv,
    float* __restrict__ c_io,
    unsigned short* __restrict__ hh, unsigned short* __restrict__ hl,
    unsigned short* __restrict__ ch, unsigned short* __restrict__ cl)
{
    __shared__ __align__(16) unsigned short sA[2][128 * 32];
    __shared__ __align__(16) unsigned short sB[2][128 * 32];
    const int tid  = threadIdx.x;
    const int lane = tid & 63;
    const int wv   = tid >> 6;
    const int wm   = wv & 1, wn = wv >> 1;
    const int row0 = blockIdx.x * 128;
    const int by32 = blockIdx.y * 32;

    f32x4 acc[4][4];   // [m-tile][gate]
#pragma unroll
    for (int i = 0; i < 4; i++)
#pragma unroll
        for (int g = 0; g < 4; g++) acc[i][g] = (f32x4){0.f, 0.f, 0.f, 0.f};

    const int lrow = lane >> 2;
    const int lcol = (lane & 3) * 8;
    const int q8   = (lane >> 4) * 8;
    const int l15  = lane & 15;

#pragma unroll
    for (int sgi = 0; sgi < NSEG; ++sgi) {
        const SegB sg = (sgi == 0) ? s0 : s1;
        const int K = sg.K;
        for (int k0 = 0; k0 < K; k0 += 32) {
#pragma unroll
            for (int c = wv; c < 8; c += 4) {
                const int r = c * 16 + lrow;
                const size_t gA = (size_t)(row0 + r) * sg.lda + k0 + lcol;
                const int lo = c * 512 + lane * 8;
                async16(sg.Ah + gA, &sA[0][lo]);
                async16(sg.Al + gA, &sA[1][lo]);
            }
#pragma unroll
            for (int cc = wv; cc < 8; cc += 4) {
                const int g  = cc >> 1;
                const int jj = (cc & 1) * 16 + lrow;
                const int rowg = g * 512 + by32 + jj;
                const size_t gB = (size_t)rowg * sg.ldb + k0 + lcol;
                const int lo = cc * 512 + lane * 8;
                async16(sg.Bh + gB, &sB[0][lo]);
                async16(sg.Bl + gB, &sB[1][lo]);
            }
            __syncthreads();
            short8 ah[4], al[4], bh[4], bl[4];
#pragma unroll
            for (int i = 0; i < 4; i++) {
                const int m = wm * 64 + i * 16 + l15;
                ah[i] = *reinterpret_cast<const short8*>(&sA[0][m * 32 + q8]);
                al[i] = *reinterpret_cast<const short8*>(&sA[1][m * 32 + q8]);
            }
#pragma unroll
            for (int g = 0; g < 4; g++) {
                const int n = g * 32 + wn * 16 + l15;
                bh[g] = *reinterpret_cast<const short8*>(&sB[0][n * 32 + q8]);
                bl[g] = *reinterpret_cast<const short8*>(&sB[1][n * 32 + q8]);
            }
#pragma unroll
            for (int i = 0; i < 4; i++)
#pragma unroll
                for (int g = 0; g < 4; g++) {
                    acc[i][g] = __builtin_amdgcn_mfma_f32_16x16x32_bf16(ah[i], bh[g], acc[i][g], 0, 0, 0);
                    acc[i][g] = __builtin_amdgcn_mfma_f32_16x16x32_bf16(ah[i], bl[g], acc[i][g], 0, 0, 0);
                    acc[i][g] = __builtin_amdgcn_mfma_f32_16x16x32_bf16(al[i], bh[g], acc[i][g], 0, 0, 0);
                }
            __syncthreads();
        }
    }
    // ---- fused LSTM epilogue ----
    const int j = by32 + wn * 16 + l15;          // 0..511
    const float b0 = bias[j],            b1 = bias[Hh + j];
    const float b2 = bias[2 * Hh + j],   b3 = bias[3 * Hh + j];
    float w0 = 0.f, w1 = 0.f, w2 = 0.f, w3 = 0.f;
    if (TA) { w0 = wy[j]; w1 = wy[Hh + j]; w2 = wy[2 * Hh + j]; w3 = wy[3 * Hh + j]; }
#pragma unroll
    for (int i = 0; i < 4; i++) {
        const int rbase = row0 + wm * 64 + i * 16 + (lane >> 4) * 4;
#pragma unroll
        for (int r = 0; r < 4; r++) {
            const int row = rbase + r;
            float gi = acc[i][0][r] + b0;
            float gf = acc[i][1][r] + b1;
            float gg = acc[i][2][r] + b2;
            float go = acc[i][3][r] + b3;
            if (TA) {
                const float yb = yv[row];
                gi += yb * w0; gf += yb * w1; gg += yb * w2; go += yb * w3;
            }
            const float i_ = sigm(gi), f_ = sigm(gf), gv = tanhf(gg), o_ = sigm(go);
            const size_t idx = (size_t)row * Hh + j;
            const float cp = ZC ? 0.0f : c_io[idx];
            const float c = f_ * cp + i_ * gv;
            c_io[idx] = c;
            const float h = o_ * tanhf(c);
            const unsigned short hb = f2bf(h);
            hh[idx] = hb;
            hl[idx] = f2bf(h - bf2f(hb));
            if (!TA) {
                const unsigned short cb = f2bf(c);
                ch[idx] = cb;
                cl[idx] = f2bf(c - bf2f(cb));
            }
        }
    }
}

// ============ weight prep: W[K][N] fp32 -> Th,Tl [N][K] bf16 ============
__global__ __launch_bounds__(256) void splitT_k(const float* __restrict__ W,
                                                unsigned short* __restrict__ Th,
                                                unsigned short* __restrict__ Tl,
                                                int Kd, int Nd)
{
    __shared__ float tile[32][33];
    const int bk = blockIdx.x * 32, bn = blockIdx.y * 32;
    const int tid = threadIdx.x;
    const int r = tid >> 3, c4 = (tid & 7) * 4;
    const float4 v = *reinterpret_cast<const float4*>(&W[(size_t)(bk + r) * Nd + bn + c4]);
    tile[r][c4 + 0] = v.x; tile[r][c4 + 1] = v.y;
    tile[r][c4 + 2] = v.z; tile[r][c4 + 3] = v.w;
    __syncthreads();
    const int n = r, k4 = c4;
    ushort4 hq, lq;
    unsigned short* hp = (unsigned short*)&hq;
    unsigned short* lp = (unsigned short*)&lq;
#pragma unroll
    for (int q = 0; q < 4; q++) {
        float x = tile[k4 + q][n];
        unsigned short h = f2bf(x);
        hp[q] = h;
        lp[q] = f2bf(x - bf2f(h));
    }
    *reinterpret_cast<ushort4*>(&Th[(size_t)(bn + n) * Kd + bk + k4]) = hq;
    *reinterpret_cast<ushort4*>(&Tl[(size_t)(bn + n) * Kd + bk + k4]) = lq;
}

// ---- ta_Wa [512][16] -> WaT hi/lo [16][512] ----
__global__ __launch_bounds__(256) void splitWa_k(const float* __restrict__ W,
                                                 unsigned short* __restrict__ Th,
                                                 unsigned short* __restrict__ Tl)
{
    int idx = blockIdx.x * 256 + threadIdx.x;   // 8192
    int n = idx >> 9, k = idx & 511;
    float x = W[(size_t)k * 16 + n];
    unsigned short h = f2bf(x);
    Th[idx] = h;
    Tl[idx] = f2bf(x - bf2f(h));
}

// -------- init: y0 = X[:,0,255]; split X[:,0,:] --------
__global__ __launch_bounds__(256) void init_k(const float* __restrict__ X,
                                              unsigned short* __restrict__ xsh,
                                              unsigned short* __restrict__ xsl,
                                              float* __restrict__ yv)
{
    int idx = blockIdx.x * 256 + threadIdx.x;
    int b = idx >> 8, d = idx & 255;
    float xv = X[(size_t)b * (Ss * Dd) + d];
    unsigned short hb = f2bf(xv);
    xsh[idx] = hb;
    xsl[idx] = f2bf(xv - bf2f(hb));
    if (d == Dd - 1) yv[b] = xv;
}

// ------- softmax over D, scale by x_t -> xt hi/lo; piggyback split X[:,t+1] -------
template<int SPLITX>
__global__ __launch_bounds__(256) void softmax_xt_k(const float* __restrict__ a,
                                                    const float* __restrict__ X,
                                                    unsigned short* __restrict__ xh,
                                                    unsigned short* __restrict__ xl,
                                                    unsigned short* __restrict__ xsh,
                                                    unsigned short* __restrict__ xsl,
                                                    int t)
{
    int b = blockIdx.x, tid = threadIdx.x;
    __shared__ float red[256];
    float v = a[(size_t)b * Dd + tid];
    red[tid] = v; __syncthreads();
    for (int s = 128; s > 0; s >>= 1) {
        if (tid < s) red[tid] = fmaxf(red[tid], red[tid + s]);
        __syncthreads();
    }
    float mx = red[0]; __syncthreads();
    float e = expf(v - mx);
    red[tid] = e; __syncthreads();
    for (int s = 128; s > 0; s >>= 1) {
        if (tid < s) red[tid] += red[tid + s];
        __syncthreads();
    }
    float inv = 1.0f / red[0];
    float xv = e * inv * X[(size_t)b * Ss * Dd + (size_t)t * Dd + tid];
    unsigned short h = f2bf(xv);
    xh[(size_t)b * Dd + tid] = h;
    xl[(size_t)b * Dd + tid] = f2bf(xv - bf2f(h));
    if (SPLITX) {
        float xn = X[(size_t)b * Ss * Dd + (size_t)(t + 1) * Dd + tid];
        unsigned short xb = f2bf(xn);
        xsh[(size_t)b * Dd + tid] = xb;
        xsl[(size_t)b * Dd + tid] = f2bf(xn - bf2f(xb));
    }
}

// ------- beta: MFMA logits (65536x512 @ WaT 16x512) + fused tanh/@Va/softmax -------
__global__ __launch_bounds__(256) void beta_k(const unsigned short* __restrict__ H3h,
                                              const unsigned short* __restrict__ H3l,
                                              const unsigned short* __restrict__ WaTh,
                                              const unsigned short* __restrict__ WaTl,
                                              const float* __restrict__ taba,
                                              const float* __restrict__ taVa,
                                              float* __restrict__ beta)
{
    __shared__ __align__(16) unsigned short sW[2][16 * 512];   // 32 KB
    __shared__ __align__(16) unsigned short sA[2][128 * 32];   // 16 KB
    __shared__ float tt[128][17];                               // 8.5 KB
    __shared__ float Vas[256];
    const int tid  = threadIdx.x;
    const int lane = tid & 63;
    const int wv   = tid >> 6;
    const int lrow = lane >> 2;
    const int lcol = (lane & 3) * 8;
    const int q8   = (lane >> 4) * 8;
    const int l15  = lane & 15;
    const size_t row0 = (size_t)blockIdx.x * 128;

    // stage WaT (hi/lo) fully; wave-uniform base + lane*16B
#pragma unroll
    for (int it = 0; it < 4; ++it) {
        const int lo = wv * 2048 + it * 512 + lane * 8;
        async16(WaTh + lo, &sW[0][lo]);
        async16(WaTl + lo, &sW[1][lo]);
    }
    Vas[tid] = taVa[tid];

    f32x4 acc[2];
    acc[0] = (f32x4){0.f, 0.f, 0.f, 0.f};
    acc[1] = (f32x4){0.f, 0.f, 0.f, 0.f};

    for (int kc = 0; kc < 16; ++kc) {
        const int k0 = kc * 32;
#pragma unroll
        for (int c = wv; c < 8; c += 4) {
            const int r = c * 16 + lrow;
            const size_t gA = (row0 + r) * Hh + k0 + lcol;
            const int lo = c * 512 + lane * 8;
            async16(H3h + gA, &sA[0][lo]);
            async16(H3l + gA, &sA[1][lo]);
        }
        __syncthreads();
        const short8 bh = *reinterpret_cast<const short8*>(&sW[0][l15 * 512 + k0 + q8]);
        const short8 bl = *reinterpret_cast<const short8*>(&sW[1][l15 * 512 + k0 + q8]);
#pragma unroll
        for (int i = 0; i < 2; i++) {
            const int m = wv * 32 + i * 16 + l15;
            const short8 ah = *reinterpret_cast<const short8*>(&sA[0][m * 32 + q8]);
            const short8 al = *reinterpret_cast<const short8*>(&sA[1][m * 32 + q8]);
            acc[i] = __builtin_amdgcn_mfma_f32_16x16x32_bf16(ah, bh, acc[i], 0, 0, 0);
            acc[i] = __builtin_amdgcn_mfma_f32_16x16x32_bf16(ah, bl, acc[i], 0, 0, 0);
            acc[i] = __builtin_amdgcn_mfma_f32_16x16x32_bf16(al, bh, acc[i], 0, 0, 0);
        }
        __syncthreads();
    }
    const float ba = taba[l15];
#pragma unroll
    for (int i = 0; i < 2; i++) {
#pragma unroll
        for (int r = 0; r < 4; r++) {
            const int rl = wv * 32 + i * 16 + (lane >> 4) * 4 + r;
            tt[rl][l15] = tanhf(acc[i][r] + ba);
        }
    }
    __syncthreads();
    if (tid < 128) {
        float tv[16];
#pragma unroll
        for (int m = 0; m < 16; m++) tv[m] = tt[tid][m];
        float l[16];
        float mx = -1e30f;
#pragma unroll
        for (int n = 0; n < 16; n++) {
            float s = 0.0f;
#pragma unroll
            for (int m = 0; m < 16; m++) s = fmaf(tv[m], Vas[m * 16 + n], s);
            l[n] = s;
            mx = fmaxf(mx, s);
        }
        float sum = 0.0f;
#pragma unroll
        for (int n = 0; n < 16; n++) { l[n] = expf(l[n] - mx); sum += l[n]; }
        const float inv = 1.0f / sum;
        float* bp = beta + (row0 + tid) * 16;
#pragma unroll
        for (int n4 = 0; n4 < 4; n4++) {
            float4 v = { l[n4 * 4] * inv, l[n4 * 4 + 1] * inv,
                         l[n4 * 4 + 2] * inv, l[n4 * 4 + 3] * inv };
            *reinterpret_cast<float4*>(bp + n4 * 4) = v;
        }
    }
}

// ------- h_ctx for ALL t in one dispatch, in-place into H3 -------
__global__ __launch_bounds__(256) void hctx_all_k(unsigned short* __restrict__ H3h,
                                                  unsigned short* __restrict__ H3l,
                                                  const float* __restrict__ beta)
{
    int b = blockIdx.x, tid = threadIdx.x;
    __shared__ float Hs[16][516];
    __shared__ float bs[16][16];
    for (int i = tid; i < 16 * 512; i += 256) {
        int s = i >> 9, h = i & 511;
        size_t o = ((size_t)s * Bb + b) * Hh + h;
        Hs[s][h] = bf2f(H3h[o]) + bf2f(H3l[o]);
    }
    {
        int t = tid >> 4, s = tid & 15;
        bs[t][s] = beta[((size_t)t * Bb + b) * 16 + s];
    }
    __syncthreads();
#pragma unroll
    for (int t = 0; t < 16; t++) {
        for (int h = tid; h < Hh; h += 256) {
            float a = 0.0f;
#pragma unroll
            for (int s = 0; s < 16; s++) a = fmaf(bs[t][s], Hs[s][h], a);
            unsigned short hb = f2bf(a);
            size_t o = ((size_t)t * Bb + b) * Hh + h;
            H3h[o] = hb;
            H3l[o] = f2bf(a - bf2f(hb));
        }
    }
}

// ---------------- y = lh @ fc_W.T + fc_b (lh from hi/lo) ----------------
__global__ __launch_bounds__(256) void y_k(const unsigned short* __restrict__ hh,
                                           const unsigned short* __restrict__ hl,
                                           const float* __restrict__ fcW,
                                           const float* __restrict__ fcb,
                                           float* __restrict__ yv,
                                           float* __restrict__ outp)
{
    int b = blockIdx.x, tid = threadIdx.x;
    size_t o = (size_t)b * Hh + tid;
    float h0 = bf2f(hh[o]) + bf2f(hl[o]);
    float h1 = bf2f(hh[o + 256]) + bf2f(hl[o + 256]);
    float p = h0 * fcW[tid] + h1 * fcW[tid + 256];
#pragma unroll
    for (int off = 32; off > 0; off >>= 1) p += __shfl_down(p, off, 64);
    __shared__ float wred[4];
    if ((tid & 63) == 0) wred[tid >> 6] = p;
    __syncthreads();
    if (tid == 0) {
        float y = fcb[0] + wred[0] + wred[1] + wred[2] + wred[3];
        yv[b] = y;
        if (outp) outp[b] = y;
    }
}

extern "C" void kernel_launch(void* const* d_in, const int* in_sizes, int n_in,
                              void* d_out, int out_size, void* d_ws, size_t ws_size,
                              hipStream_t stream)
{
    (void)in_sizes; (void)n_in; (void)out_size; (void)ws_size;
    const float* X     = (const float*)d_in[0];
    const float* sa_W  = (const float*)d_in[1];
    const float* sa_U  = (const float*)d_in[2];
    const float* sa_b  = (const float*)d_in[3];
    const float* sa_Wa = (const float*)d_in[4];
    const float* sa_Ua = (const float*)d_in[5];
    const float* sa_ba = (const float*)d_in[6];
    const float* sa_Va = (const float*)d_in[7];
    const float* ta_Wa = (const float*)d_in[8];
    // d_in[9] = ta_Ua : multiplied by s0 == 0 -> unused
    const float* ta_ba = (const float*)d_in[10];
    const float* ta_Va = (const float*)d_in[11];
    const float* ta_W  = (const float*)d_in[12];
    const float* ta_U  = (const float*)d_in[13];
    const float* ta_b  = (const float*)d_in[14];
    const float* ta_Wy = (const float*)d_in[15];
    const float* fc_W  = (const float*)d_in[16];
    const float* fc_b  = (const float*)d_in[17];

    char* base = (char*)d_ws;
    size_t off = 0;
    auto alloc = [&](size_t bytes) {
        void* p = base + off; off += (bytes + 255) & ~(size_t)255; return p;
    };
    const size_t BH = (size_t)Bb * Hh;          // 2M elems
    float* avxt = (float*)alloc((size_t)Bb * Dd * 4);                   //  4 MiB
    unsigned short* H3h = (unsigned short*)alloc((size_t)Ss * BH * 2);  // 64 MiB
    unsigned short* H3l = (unsigned short*)alloc((size_t)Ss * BH * 2);  // 64 MiB
    float* cbuf = (float*)alloc(BH * 4);         // 8 MiB (sa c fp32; ta: lhA alias)
    float* lc   = (float*)alloc(BH * 4);         // 8 MiB
    unsigned short* lhBh = (unsigned short*)alloc(BH * 2);              // 4 MiB
    unsigned short* lhBl = (unsigned short*)alloc(BH * 2);              // 4 MiB
    unsigned short* xth = (unsigned short*)alloc((size_t)Bb * Dd * 2);  // 2 MiB
    unsigned short* xtl = (unsigned short*)alloc((size_t)Bb * Dd * 2);  // 2 MiB
    unsigned short* xsh = (unsigned short*)alloc((size_t)Bb * Dd * 2);  // 2 MiB
    unsigned short* xsl = (unsigned short*)alloc((size_t)Bb * Dd * 2);  // 2 MiB
    unsigned short* ch  = (unsigned short*)alloc(BH * 2);               // 4 MiB
    unsigned short* cl  = (unsigned short*)alloc(BH * 2);               // 4 MiB
    unsigned short* tmph = (unsigned short*)alloc((size_t)Bb * Dd * 2); // 2 MiB
    unsigned short* tmpl = (unsigned short*)alloc((size_t)Bb * Dd * 2); // 2 MiB
    unsigned short* saWth = (unsigned short*)alloc((size_t)Dd * 4 * Hh * 2);
    unsigned short* saWtl = (unsigned short*)alloc((size_t)Dd * 4 * Hh * 2);
    unsigned short* saUth = (unsigned short*)alloc((size_t)Hh * 4 * Hh * 2);
    unsigned short* saUtl = (unsigned short*)alloc((size_t)Hh * 4 * Hh * 2);
    unsigned short* taWth = (unsigned short*)alloc((size_t)Hh * 4 * Hh * 2);
    unsigned short* taWtl = (unsigned short*)alloc((size_t)Hh * 4 * Hh * 2);
    unsigned short* taUth = (unsigned short*)alloc((size_t)Hh * 4 * Hh * 2);
    unsigned short* taUtl = (unsigned short*)alloc((size_t)Hh * 4 * Hh * 2);
    unsigned short* WaTh = (unsigned short*)alloc((size_t)Dd * Dd * 2);
    unsigned short* WaTl = (unsigned short*)alloc((size_t)Dd * Dd * 2);
    unsigned short* UaTh = (unsigned short*)alloc((size_t)2 * Hh * Dd * 2);
    unsigned short* UaTl = (unsigned short*)alloc((size_t)2 * Hh * Dd * 2);
    unsigned short* VaTh = (unsigned short*)alloc((size_t)Dd * Dd * 2);
    unsigned short* VaTl = (unsigned short*)alloc((size_t)Dd * Dd * 2);
    unsigned short* tWaTh = (unsigned short*)alloc((size_t)16 * Hh * 2);
    unsigned short* tWaTl = (unsigned short*)alloc((size_t)16 * Hh * 2);
    float* yv = (float*)alloc((size_t)Bb * 4);
    // aliases (dead at time of reuse):
    float* beta = (float*)xth;                    // 4 MiB over xth+xtl (ta phase)
    unsigned short* lhAh = (unsigned short*)cbuf; // ta phase (cbuf dead)
    unsigned short* lhAl = (unsigned short*)cbuf + BH;
    unsigned short* lhh[2] = { lhAh, lhBh };
    unsigned short* lhl[2] = { lhAl, lhBl };
    // total ~188 MiB

    // ---- weight prep ----
    splitT_k<<<dim3(Dd / 32, (4 * Hh) / 32), 256, 0, stream>>>(sa_W, saWth, saWtl, Dd, 4 * Hh);
    splitT_k<<<dim3(Hh / 32, (4 * Hh) / 32), 256, 0, stream>>>(sa_U, saUth, saUtl, Hh, 4 * Hh);
    splitT_k<<<dim3(Hh / 32, (4 * Hh) / 32), 256, 0, stream>>>(ta_W, taWth, taWtl, Hh, 4 * Hh);
    splitT_k<<<dim3(Hh / 32, (4 * Hh) / 32), 256, 0, stream>>>(ta_U, taUth, taUtl, Hh, 4 * Hh);
    splitT_k<<<dim3(Dd / 32, Dd / 32), 256, 0, stream>>>(sa_Wa, WaTh, WaTl, Dd, Dd);
    splitT_k<<<dim3((2 * Hh) / 32, Dd / 32), 256, 0, stream>>>(sa_Ua, UaTh, UaTl, 2 * Hh, Dd);
    splitT_k<<<dim3(Dd / 32, Dd / 32), 256, 0, stream>>>(sa_Va, VaTh, VaTl, Dd, Dd);
    splitWa_k<<<dim3(32), 256, 0, stream>>>(ta_Wa, tWaTh, tWaTl);
    init_k<<<dim3((Bb * Dd) / 256), 256, 0, stream>>>(X, xsh, xsl, yv);

    const dim3 agrid(Bb / 64, Dd / 64);          // 64 x 4
    const dim3 ggrid(Bb / 128, Hh / 32);         // 32 x 16

    // ---- spatial-attention LSTM ----
    for (int t = 0; t < Ss; ++t) {
        // tmp = tanh(x_t @ sa_Wa + h @ Ua[:HS] + c @ Ua[HS:] + sa_ba) [MFMA]
        SegB a0{ xsh, xsl, WaTh, WaTl, Dd, Dd, Dd };
        if (t == 0) {
            gemm_mfma_k<64, 64, 1, 1><<<agrid, 256, 0, stream>>>(
                a0, a0, a0, sa_ba, nullptr, tmph, tmpl, Dd);
        } else {
            SegB a1{ H3h + (size_t)(t - 1) * BH, H3l + (size_t)(t - 1) * BH,
                     UaTh, UaTl, Hh, 2 * Hh, Hh };
            SegB a2{ ch, cl, UaTh + Hh, UaTl + Hh, Hh, 2 * Hh, Hh };
            gemm_mfma_k<64, 64, 3, 1><<<agrid, 256, 0, stream>>>(
                a0, a1, a2, sa_ba, nullptr, tmph, tmpl, Dd);
        }

        // av = tmp @ sa_Va  [MFMA]
        SegB v0{ tmph, tmpl, VaTh, VaTl, Dd, Dd, Dd };
        gemm_mfma_k<64, 64, 1, 0><<<agrid, 256, 0, stream>>>(
            v0, v0, v0, nullptr, avxt, nullptr, nullptr, Dd);

        if (t < Ss - 1)
            softmax_xt_k<1><<<Bb, 256, 0, stream>>>(avxt, X, xth, xtl, xsh, xsl, t);
        else
            softmax_xt_k<0><<<Bb, 256, 0, stream>>>(avxt, X, xth, xtl, xsh, xsl, t);

        // gates + LSTM fused
        SegB g0{ xth, xtl, saWth, saWtl, Dd, Dd, Dd };
        if (t == 0) {
            gemm_gates_k<1, 1, 0><<<ggrid, 256, 0, stream>>>(
                g0, g0, sa_b, nullptr, nullptr, cbuf,
                H3h + (size_t)t * BH, H3l + (size_t)t * BH, ch, cl);
        } else {
            SegB g1{ H3h + (size_t)(t - 1) * BH, H3l + (size_t)(t - 1) * BH,
                     saUth, saUtl, Hh, Hh, Hh };
            gemm_gates_k<2, 0, 0><<<ggrid, 256, 0, stream>>>(
                g0, g1, sa_b, nullptr, nullptr, cbuf,
                H3h + (size_t)t * BH, H3l + (size_t)t * BH, ch, cl);
        }
    }

    // ---- temporal attention: beta (MFMA+fused finish), then h_ctx in place ----
    beta_k<<<dim3((Ss * Bb) / 128), 256, 0, stream>>>(
        H3h, H3l, tWaTh, tWaTl, ta_ba, ta_Va, beta);
    hctx_all_k<<<Bb, 256, 0, stream>>>(H3h, H3l, beta);

    // ---- temporal LSTM (H3 planes now hold h_ctx); lh ping-pong ----
    for (int t = 0; t < Ss; ++t) {
        SegB g0{ H3h + (size_t)t * BH, H3l + (size_t)t * BH,
                 taWth, taWtl, Hh, Hh, Hh };
        const int po = t & 1;
        if (t == 0) {
            gemm_gates_k<1, 1, 1><<<ggrid, 256, 0, stream>>>(
                g0, g0, ta_b, ta_Wy, yv, lc, lhh[0], lhl[0], nullptr, nullptr);
        } else {
            SegB g1{ lhh[(t - 1) & 1], lhl[(t - 1) & 1], taUth, taUtl, Hh, Hh, Hh };
            gemm_gates_k<2, 0, 1><<<ggrid, 256, 0, stream>>>(
                g0, g1, ta_b, ta_Wy, yv, lc, lhh[po], lhl[po], nullptr, nullptr);
        }
        y_k<<<Bb, 256, 0, stream>>>(lhh[po], lhl[po], fc_W, fc_b, yv,
                                    (t == Ss - 1) ? (float*)d_out : nullptr);
    }
}

// Round 7
// 2413.069 us; speedup vs baseline: 3.3101x; 1.0330x over previous
//
#include <hip/hip_runtime.h>

// STA-LSTM forward. B=4096 S=16 D=256 HS=HT=512. Output y (B,1) fp32.
// R7 (on R6's fused structure):
//   - A1/A2 attention GEMMs: 64x64 -> 32x64 tiles (grid 256 -> 512 blocks,
//     2 blocks/CU so staging overlaps compute; 64x64 ran 1/CU ~250 TF eff).
//   - hctx_all_k: ushort4/float4 vectorized (was scalar-convert bound,
//     VALUBusy 47% @ 2.67 TB/s).
//   Gates kernels (at ~874 TF m97 plateau), beta, precision scheme unchanged.
// ws: ~188 MiB.

constexpr int Bb = 4096;
constexpr int Ss = 16;
constexpr int Dd = 256;
constexpr int Hh = 512;   // HS == HT

typedef __attribute__((ext_vector_type(8))) short short8;
typedef __attribute__((ext_vector_type(4))) float f32x4;

__device__ __forceinline__ float sigm(float x) { return 1.0f / (1.0f + expf(-x)); }

__device__ __forceinline__ unsigned short f2bf(float x) {   // RNE fp32->bf16 bits
    unsigned int u = __float_as_uint(x);
    u = (u + 0x7fffu + ((u >> 16) & 1u)) >> 16;
    return (unsigned short)u;
}
__device__ __forceinline__ float bf2f(unsigned short h) {
    return __uint_as_float(((unsigned int)h) << 16);
}
__device__ __forceinline__ void async16(const void* g, void* l) {
    __builtin_amdgcn_global_load_lds(
        (const __attribute__((address_space(1))) void*)g,
        (__attribute__((address_space(3))) void*)l, 16, 0, 0);
}

struct SegB { const unsigned short* Ah; const unsigned short* Al;
              const unsigned short* Bh; const unsigned short* Bl;
              int lda; int ldb; int K; };

// ================= generic split-bf16 MFMA GEMM (attention path) ==========
// C[M,N] = sum_seg (Ah+Al)[M,K] @ (Bh+Bl)[N,K]^T, dropping Al*Bl.
// EPI=0: store fp32 C. EPI=1: v=tanh(acc+bias[col]); split-store to Th/Tl.
template<int BM, int BN, int NSEG, int EPI>
__global__ __launch_bounds__(256) void gemm_mfma_k(
    SegB s0, SegB s1, SegB s2,
    const float* __restrict__ bias,
    float* __restrict__ C,
    unsigned short* __restrict__ Th, unsigned short* __restrict__ Tl,
    int ldc)
{
    constexpr int WM = BM / 2, WN = BN / 2;
    constexpr int FI = WM / 16, FJ = WN / 16;
    __shared__ __align__(16) unsigned short sA[2][BM * 32];
    __shared__ __align__(16) unsigned short sB[2][BN * 32];
    const int tid  = threadIdx.x;
    const int lane = tid & 63;
    const int wv   = tid >> 6;
    const int wm   = wv & 1, wn = wv >> 1;
    const int row0 = blockIdx.x * BM;
    const int col0 = blockIdx.y * BN;

    f32x4 acc[FI][FJ];
#pragma unroll
    for (int i = 0; i < FI; i++)
#pragma unroll
        for (int j = 0; j < FJ; j++) acc[i][j] = (f32x4){0.f, 0.f, 0.f, 0.f};

    const int lrow = lane >> 2;
    const int lcol = (lane & 3) * 8;
    const int q8   = (lane >> 4) * 8;
    const int l15  = lane & 15;

#pragma unroll
    for (int sgi = 0; sgi < NSEG; ++sgi) {
        const SegB sg = (sgi == 0) ? s0 : ((sgi == 1) ? s1 : s2);
        const int K = sg.K;
        for (int k0 = 0; k0 < K; k0 += 32) {
#pragma unroll
            for (int c = wv; c < BM / 16; c += 4) {
                const int r = c * 16 + lrow;
                const size_t gA = (size_t)(row0 + r) * sg.lda + k0 + lcol;
                const int lo = c * 512 + lane * 8;
                async16(sg.Ah + gA, &sA[0][lo]);
                async16(sg.Al + gA, &sA[1][lo]);
            }
#pragma unroll
            for (int c = wv; c < BN / 16; c += 4) {
                const int r = c * 16 + lrow;
                const size_t gB = (size_t)(col0 + r) * sg.ldb + k0 + lcol;
                const int lo = c * 512 + lane * 8;
                async16(sg.Bh + gB, &sB[0][lo]);
                async16(sg.Bl + gB, &sB[1][lo]);
            }
            __syncthreads();
            short8 ah[FI], al[FI], bh[FJ], bl[FJ];
#pragma unroll
            for (int i = 0; i < FI; i++) {
                const int m = wm * WM + i * 16 + l15;
                ah[i] = *reinterpret_cast<const short8*>(&sA[0][m * 32 + q8]);
                al[i] = *reinterpret_cast<const short8*>(&sA[1][m * 32 + q8]);
            }
#pragma unroll
            for (int j = 0; j < FJ; j++) {
                const int n = wn * WN + j * 16 + l15;
                bh[j] = *reinterpret_cast<const short8*>(&sB[0][n * 32 + q8]);
                bl[j] = *reinterpret_cast<const short8*>(&sB[1][n * 32 + q8]);
            }
#pragma unroll
            for (int i = 0; i < FI; i++)
#pragma unroll
                for (int j = 0; j < FJ; j++) {
                    acc[i][j] = __builtin_amdgcn_mfma_f32_16x16x32_bf16(ah[i], bh[j], acc[i][j], 0, 0, 0);
                    acc[i][j] = __builtin_amdgcn_mfma_f32_16x16x32_bf16(ah[i], bl[j], acc[i][j], 0, 0, 0);
                    acc[i][j] = __builtin_amdgcn_mfma_f32_16x16x32_bf16(al[i], bh[j], acc[i][j], 0, 0, 0);
                }
            __syncthreads();
        }
    }
#pragma unroll
    for (int i = 0; i < FI; i++) {
#pragma unroll
        for (int j = 0; j < FJ; j++) {
            const int col = col0 + wn * WN + j * 16 + l15;
#pragma unroll
            for (int r = 0; r < 4; r++) {
                const int row = row0 + wm * WM + i * 16 + (lane >> 4) * 4 + r;
                float v = acc[i][j][r];
                if (EPI == 1) {
                    v = tanhf(v + bias[col]);
                    unsigned short hb = f2bf(v);
                    Th[(size_t)row * ldc + col] = hb;
                    Tl[(size_t)row * ldc + col] = f2bf(v - bf2f(hb));
                } else {
                    C[(size_t)row * ldc + col] = v;
                }
            }
        }
    }
}

// ============ fused gates GEMM + LSTM pointwise ============
// Block = (128 batch rows) x (32 j). B-tile = rows {g*512 + j0+jj} of W^T
// for g=0..3 -> each thread ends with gi/gf/gg/go for its (row,j) pairs.
// TA=0 (sa): c fp32 in-place + split c -> ch/cl, h -> hh/hl (H3 plane).
// TA=1 (ta): + y_prev*wy rank-1; c fp32 in-place (lc); h -> hh/hl (lh pong).
template<int NSEG, int ZC, int TA>
__global__ __launch_bounds__(256) void gemm_gates_k(
    SegB s0, SegB s1,
    const float* __restrict__ bias,
    const float* __restrict__ wy,
    const float* __restrict__ yv,
    float* __restrict__ c_io,
    unsigned short* __restrict__ hh, unsigned short* __restrict__ hl,
    unsigned short* __restrict__ ch, unsigned short* __restrict__ cl)
{
    __shared__ __align__(16) unsigned short sA[2][128 * 32];
    __shared__ __align__(16) unsigned short sB[2][128 * 32];
    const int tid  = threadIdx.x;
    const int lane = tid & 63;
    const int wv   = tid >> 6;
    const int wm   = wv & 1, wn = wv >> 1;
    const int row0 = blockIdx.x * 128;
    const int by32 = blockIdx.y * 32;

    f32x4 acc[4][4];   // [m-tile][gate]
#pragma unroll
    for (int i = 0; i < 4; i++)
#pragma unroll
        for (int g = 0; g < 4; g++) acc[i][g] = (f32x4){0.f, 0.f, 0.f, 0.f};

    const int lrow = lane >> 2;
    const int lcol = (lane & 3) * 8;
    const int q8   = (lane >> 4) * 8;
    const int l15  = lane & 15;

#pragma unroll
    for (int sgi = 0; sgi < NSEG; ++sgi) {
        const SegB sg = (sgi == 0) ? s0 : s1;
        const int K = sg.K;
        for (int k0 = 0; k0 < K; k0 += 32) {
#pragma unroll
            for (int c = wv; c < 8; c += 4) {
                const int r = c * 16 + lrow;
                const size_t gA = (size_t)(row0 + r) * sg.lda + k0 + lcol;
                const int lo = c * 512 + lane * 8;
                async16(sg.Ah + gA, &sA[0][lo]);
                async16(sg.Al + gA, &sA[1][lo]);
            }
#pragma unroll
            for (int cc = wv; cc < 8; cc += 4) {
                const int g  = cc >> 1;
                const int jj = (cc & 1) * 16 + lrow;
                const int rowg = g * 512 + by32 + jj;
                const size_t gB = (size_t)rowg * sg.ldb + k0 + lcol;
                const int lo = cc * 512 + lane * 8;
                async16(sg.Bh + gB, &sB[0][lo]);
                async16(sg.Bl + gB, &sB[1][lo]);
            }
            __syncthreads();
            short8 ah[4], al[4], bh[4], bl[4];
#pragma unroll
            for (int i = 0; i < 4; i++) {
                const int m = wm * 64 + i * 16 + l15;
                ah[i] = *reinterpret_cast<const short8*>(&sA[0][m * 32 + q8]);
                al[i] = *reinterpret_cast<const short8*>(&sA[1][m * 32 + q8]);
            }
#pragma unroll
            for (int g = 0; g < 4; g++) {
                const int n = g * 32 + wn * 16 + l15;
                bh[g] = *reinterpret_cast<const short8*>(&sB[0][n * 32 + q8]);
                bl[g] = *reinterpret_cast<const short8*>(&sB[1][n * 32 + q8]);
            }
#pragma unroll
            for (int i = 0; i < 4; i++)
#pragma unroll
                for (int g = 0; g < 4; g++) {
                    acc[i][g] = __builtin_amdgcn_mfma_f32_16x16x32_bf16(ah[i], bh[g], acc[i][g], 0, 0, 0);
                    acc[i][g] = __builtin_amdgcn_mfma_f32_16x16x32_bf16(ah[i], bl[g], acc[i][g], 0, 0, 0);
                    acc[i][g] = __builtin_amdgcn_mfma_f32_16x16x32_bf16(al[i], bh[g], acc[i][g], 0, 0, 0);
                }
            __syncthreads();
        }
    }
    // ---- fused LSTM epilogue ----
    const int j = by32 + wn * 16 + l15;          // 0..511
    const float b0 = bias[j],            b1 = bias[Hh + j];
    const float b2 = bias[2 * Hh + j],   b3 = bias[3 * Hh + j];
    float w0 = 0.f, w1 = 0.f, w2 = 0.f, w3 = 0.f;
    if (TA) { w0 = wy[j]; w1 = wy[Hh + j]; w2 = wy[2 * Hh + j]; w3 = wy[3 * Hh + j]; }
#pragma unroll
    for (int i = 0; i < 4; i++) {
        const int rbase = row0 + wm * 64 + i * 16 + (lane >> 4) * 4;
#pragma unroll
        for (int r = 0; r < 4; r++) {
            const int row = rbase + r;
            float gi = acc[i][0][r] + b0;
            float gf = acc[i][1][r] + b1;
            float gg = acc[i][2][r] + b2;
            float go = acc[i][3][r] + b3;
            if (TA) {
                const float yb = yv[row];
                gi += yb * w0; gf += yb * w1; gg += yb * w2; go += yb * w3;
            }
            const float i_ = sigm(gi), f_ = sigm(gf), gv = tanhf(gg), o_ = sigm(go);
            const size_t idx = (size_t)row * Hh + j;
            const float cp = ZC ? 0.0f : c_io[idx];
            const float c = f_ * cp + i_ * gv;
            c_io[idx] = c;
            const float h = o_ * tanhf(c);
            const unsigned short hb = f2bf(h);
            hh[idx] = hb;
            hl[idx] = f2bf(h - bf2f(hb));
            if (!TA) {
                const unsigned short cb = f2bf(c);
                ch[idx] = cb;
                cl[idx] = f2bf(c - bf2f(cb));
            }
        }
    }
}

// ============ weight prep: W[K][N] fp32 -> Th,Tl [N][K] bf16 ============
__global__ __launch_bounds__(256) void splitT_k(const float* __restrict__ W,
                                                unsigned short* __restrict__ Th,
                                                unsigned short* __restrict__ Tl,
                                                int Kd, int Nd)
{
    __shared__ float tile[32][33];
    const int bk = blockIdx.x * 32, bn = blockIdx.y * 32;
    const int tid = threadIdx.x;
    const int r = tid >> 3, c4 = (tid & 7) * 4;
    const float4 v = *reinterpret_cast<const float4*>(&W[(size_t)(bk + r) * Nd + bn + c4]);
    tile[r][c4 + 0] = v.x; tile[r][c4 + 1] = v.y;
    tile[r][c4 + 2] = v.z; tile[r][c4 + 3] = v.w;
    __syncthreads();
    const int n = r, k4 = c4;
    ushort4 hq, lq;
    unsigned short* hp = (unsigned short*)&hq;
    unsigned short* lp = (unsigned short*)&lq;
#pragma unroll
    for (int q = 0; q < 4; q++) {
        float x = tile[k4 + q][n];
        unsigned short h = f2bf(x);
        hp[q] = h;
        lp[q] = f2bf(x - bf2f(h));
    }
    *reinterpret_cast<ushort4*>(&Th[(size_t)(bn + n) * Kd + bk + k4]) = hq;
    *reinterpret_cast<ushort4*>(&Tl[(size_t)(bn + n) * Kd + bk + k4]) = lq;
}

// ---- ta_Wa [512][16] -> WaT hi/lo [16][512] ----
__global__ __launch_bounds__(256) void splitWa_k(const float* __restrict__ W,
                                                 unsigned short* __restrict__ Th,
                                                 unsigned short* __restrict__ Tl)
{
    int idx = blockIdx.x * 256 + threadIdx.x;   // 8192
    int n = idx >> 9, k = idx & 511;
    float x = W[(size_t)k * 16 + n];
    unsigned short h = f2bf(x);
    Th[idx] = h;
    Tl[idx] = f2bf(x - bf2f(h));
}

// -------- init: y0 = X[:,0,255]; split X[:,0,:] --------
__global__ __launch_bounds__(256) void init_k(const float* __restrict__ X,
                                              unsigned short* __restrict__ xsh,
                                              unsigned short* __restrict__ xsl,
                                              float* __restrict__ yv)
{
    int idx = blockIdx.x * 256 + threadIdx.x;
    int b = idx >> 8, d = idx & 255;
    float xv = X[(size_t)b * (Ss * Dd) + d];
    unsigned short hb = f2bf(xv);
    xsh[idx] = hb;
    xsl[idx] = f2bf(xv - bf2f(hb));
    if (d == Dd - 1) yv[b] = xv;
}

// ------- softmax over D, scale by x_t -> xt hi/lo; piggyback split X[:,t+1] -------
template<int SPLITX>
__global__ __launch_bounds__(256) void softmax_xt_k(const float* __restrict__ a,
                                                    const float* __restrict__ X,
                                                    unsigned short* __restrict__ xh,
                                                    unsigned short* __restrict__ xl,
                                                    unsigned short* __restrict__ xsh,
                                                    unsigned short* __restrict__ xsl,
                                                    int t)
{
    int b = blockIdx.x, tid = threadIdx.x;
    __shared__ float red[256];
    float v = a[(size_t)b * Dd + tid];
    red[tid] = v; __syncthreads();
    for (int s = 128; s > 0; s >>= 1) {
        if (tid < s) red[tid] = fmaxf(red[tid], red[tid + s]);
        __syncthreads();
    }
    float mx = red[0]; __syncthreads();
    float e = expf(v - mx);
    red[tid] = e; __syncthreads();
    for (int s = 128; s > 0; s >>= 1) {
        if (tid < s) red[tid] += red[tid + s];
        __syncthreads();
    }
    float inv = 1.0f / red[0];
    float xv = e * inv * X[(size_t)b * Ss * Dd + (size_t)t * Dd + tid];
    unsigned short h = f2bf(xv);
    xh[(size_t)b * Dd + tid] = h;
    xl[(size_t)b * Dd + tid] = f2bf(xv - bf2f(h));
    if (SPLITX) {
        float xn = X[(size_t)b * Ss * Dd + (size_t)(t + 1) * Dd + tid];
        unsigned short xb = f2bf(xn);
        xsh[(size_t)b * Dd + tid] = xb;
        xsl[(size_t)b * Dd + tid] = f2bf(xn - bf2f(xb));
    }
}

// ------- beta: MFMA logits (65536x512 @ WaT 16x512) + fused tanh/@Va/softmax -------
__global__ __launch_bounds__(256) void beta_k(const unsigned short* __restrict__ H3h,
                                              const unsigned short* __restrict__ H3l,
                                              const unsigned short* __restrict__ WaTh,
                                              const unsigned short* __restrict__ WaTl,
                                              const float* __restrict__ taba,
                                              const float* __restrict__ taVa,
                                              float* __restrict__ beta)
{
    __shared__ __align__(16) unsigned short sW[2][16 * 512];   // 32 KB
    __shared__ __align__(16) unsigned short sA[2][128 * 32];   // 16 KB
    __shared__ float tt[128][17];                               // 8.5 KB
    __shared__ float Vas[256];
    const int tid  = threadIdx.x;
    const int lane = tid & 63;
    const int wv   = tid >> 6;
    const int lrow = lane >> 2;
    const int lcol = (lane & 3) * 8;
    const int q8   = (lane >> 4) * 8;
    const int l15  = lane & 15;
    const size_t row0 = (size_t)blockIdx.x * 128;

#pragma unroll
    for (int it = 0; it < 4; ++it) {
        const int lo = wv * 2048 + it * 512 + lane * 8;
        async16(WaTh + lo, &sW[0][lo]);
        async16(WaTl + lo, &sW[1][lo]);
    }
    Vas[tid] = taVa[tid];

    f32x4 acc[2];
    acc[0] = (f32x4){0.f, 0.f, 0.f, 0.f};
    acc[1] = (f32x4){0.f, 0.f, 0.f, 0.f};

    for (int kc = 0; kc < 16; ++kc) {
        const int k0 = kc * 32;
#pragma unroll
        for (int c = wv; c < 8; c += 4) {
            const int r = c * 16 + lrow;
            const size_t gA = (row0 + r) * Hh + k0 + lcol;
            const int lo = c * 512 + lane * 8;
            async16(H3h + gA, &sA[0][lo]);
            async16(H3l + gA, &sA[1][lo]);
        }
        __syncthreads();
        const short8 bh = *reinterpret_cast<const short8*>(&sW[0][l15 * 512 + k0 + q8]);
        const short8 bl = *reinterpret_cast<const short8*>(&sW[1][l15 * 512 + k0 + q8]);
#pragma unroll
        for (int i = 0; i < 2; i++) {
            const int m = wv * 32 + i * 16 + l15;
            const short8 ah = *reinterpret_cast<const short8*>(&sA[0][m * 32 + q8]);
            const short8 al = *reinterpret_cast<const short8*>(&sA[1][m * 32 + q8]);
            acc[i] = __builtin_amdgcn_mfma_f32_16x16x32_bf16(ah, bh, acc[i], 0, 0, 0);
            acc[i] = __builtin_amdgcn_mfma_f32_16x16x32_bf16(ah, bl, acc[i], 0, 0, 0);
            acc[i] = __builtin_amdgcn_mfma_f32_16x16x32_bf16(al, bh, acc[i], 0, 0, 0);
        }
        __syncthreads();
    }
    const float ba = taba[l15];
#pragma unroll
    for (int i = 0; i < 2; i++) {
#pragma unroll
        for (int r = 0; r < 4; r++) {
            const int rl = wv * 32 + i * 16 + (lane >> 4) * 4 + r;
            tt[rl][l15] = tanhf(acc[i][r] + ba);
        }
    }
    __syncthreads();
    if (tid < 128) {
        float tv[16];
#pragma unroll
        for (int m = 0; m < 16; m++) tv[m] = tt[tid][m];
        float l[16];
        float mx = -1e30f;
#pragma unroll
        for (int n = 0; n < 16; n++) {
            float s = 0.0f;
#pragma unroll
            for (int m = 0; m < 16; m++) s = fmaf(tv[m], Vas[m * 16 + n], s);
            l[n] = s;
            mx = fmaxf(mx, s);
        }
        float sum = 0.0f;
#pragma unroll
        for (int n = 0; n < 16; n++) { l[n] = expf(l[n] - mx); sum += l[n]; }
        const float inv = 1.0f / sum;
        float* bp = beta + (row0 + tid) * 16;
#pragma unroll
        for (int n4 = 0; n4 < 4; n4++) {
            float4 v = { l[n4 * 4] * inv, l[n4 * 4 + 1] * inv,
                         l[n4 * 4 + 2] * inv, l[n4 * 4 + 3] * inv };
            *reinterpret_cast<float4*>(bp + n4 * 4) = v;
        }
    }
}

// ------- h_ctx for ALL t in one dispatch, in-place into H3 (vectorized) -------
// Block b: stage H3[s][b][:] as float4 quads, compute all 16 t, write back
// ushort4. Writes touch only batch row b -> race-free.
__global__ __launch_bounds__(256) void hctx_all_k(unsigned short* __restrict__ H3h,
                                                  unsigned short* __restrict__ H3l,
                                                  const float* __restrict__ beta)
{
    const int b = blockIdx.x, tid = threadIdx.x;
    __shared__ float4 Hs4[16][129];   // 16 s x 128 quads (+1 pad)
    __shared__ float bs[16][16];
    for (int i = tid; i < 16 * 128; i += 256) {
        const int s = i >> 7, q = i & 127;
        const size_t o = ((size_t)s * Bb + b) * Hh + q * 4;
        const ushort4 hv = *reinterpret_cast<const ushort4*>(&H3h[o]);
        const ushort4 lv = *reinterpret_cast<const ushort4*>(&H3l[o]);
        Hs4[s][q] = (float4){ bf2f(hv.x) + bf2f(lv.x), bf2f(hv.y) + bf2f(lv.y),
                              bf2f(hv.z) + bf2f(lv.z), bf2f(hv.w) + bf2f(lv.w) };
    }
    {
        const int t = tid >> 4, s = tid & 15;
        bs[t][s] = beta[((size_t)t * Bb + b) * 16 + s];
    }
    __syncthreads();
    const int q  = tid & 127;
    const int t0 = tid >> 7;          // 0 or 1
#pragma unroll
    for (int tt = 0; tt < 8; tt++) {
        const int t = tt * 2 + t0;
        float4 a = (float4){0.f, 0.f, 0.f, 0.f};
#pragma unroll
        for (int s = 0; s < 16; s++) {
            const float w = bs[t][s];
            const float4 hv = Hs4[s][q];
            a.x = fmaf(w, hv.x, a.x); a.y = fmaf(w, hv.y, a.y);
            a.z = fmaf(w, hv.z, a.z); a.w = fmaf(w, hv.w, a.w);
        }
        ushort4 ho, lo;
        ho.x = f2bf(a.x); lo.x = f2bf(a.x - bf2f(ho.x));
        ho.y = f2bf(a.y); lo.y = f2bf(a.y - bf2f(ho.y));
        ho.z = f2bf(a.z); lo.z = f2bf(a.z - bf2f(ho.z));
        ho.w = f2bf(a.w); lo.w = f2bf(a.w - bf2f(ho.w));
        const size_t o = ((size_t)t * Bb + b) * Hh + q * 4;
        *reinterpret_cast<ushort4*>(&H3h[o]) = ho;
        *reinterpret_cast<ushort4*>(&H3l[o]) = lo;
    }
}

// ---------------- y = lh @ fc_W.T + fc_b (lh from hi/lo) ----------------
__global__ __launch_bounds__(256) void y_k(const unsigned short* __restrict__ hh,
                                           const unsigned short* __restrict__ hl,
                                           const float* __restrict__ fcW,
                                           const float* __restrict__ fcb,
                                           float* __restrict__ yv,
                                           float* __restrict__ outp)
{
    int b = blockIdx.x, tid = threadIdx.x;
    size_t o = (size_t)b * Hh + tid;
    float h0 = bf2f(hh[o]) + bf2f(hl[o]);
    float h1 = bf2f(hh[o + 256]) + bf2f(hl[o + 256]);
    float p = h0 * fcW[tid] + h1 * fcW[tid + 256];
#pragma unroll
    for (int off = 32; off > 0; off >>= 1) p += __shfl_down(p, off, 64);
    __shared__ float wred[4];
    if ((tid & 63) == 0) wred[tid >> 6] = p;
    __syncthreads();
    if (tid == 0) {
        float y = fcb[0] + wred[0] + wred[1] + wred[2] + wred[3];
        yv[b] = y;
        if (outp) outp[b] = y;
    }
}

extern "C" void kernel_launch(void* const* d_in, const int* in_sizes, int n_in,
                              void* d_out, int out_size, void* d_ws, size_t ws_size,
                              hipStream_t stream)
{
    (void)in_sizes; (void)n_in; (void)out_size; (void)ws_size;
    const float* X     = (const float*)d_in[0];
    const float* sa_W  = (const float*)d_in[1];
    const float* sa_U  = (const float*)d_in[2];
    const float* sa_b  = (const float*)d_in[3];
    const float* sa_Wa = (const float*)d_in[4];
    const float* sa_Ua = (const float*)d_in[5];
    const float* sa_ba = (const float*)d_in[6];
    const float* sa_Va = (const float*)d_in[7];
    const float* ta_Wa = (const float*)d_in[8];
    // d_in[9] = ta_Ua : multiplied by s0 == 0 -> unused
    const float* ta_ba = (const float*)d_in[10];
    const float* ta_Va = (const float*)d_in[11];
    const float* ta_W  = (const float*)d_in[12];
    const float* ta_U  = (const float*)d_in[13];
    const float* ta_b  = (const float*)d_in[14];
    const float* ta_Wy = (const float*)d_in[15];
    const float* fc_W  = (const float*)d_in[16];
    const float* fc_b  = (const float*)d_in[17];

    char* base = (char*)d_ws;
    size_t off = 0;
    auto alloc = [&](size_t bytes) {
        void* p = base + off; off += (bytes + 255) & ~(size_t)255; return p;
    };
    const size_t BH = (size_t)Bb * Hh;          // 2M elems
    float* avxt = (float*)alloc((size_t)Bb * Dd * 4);                   //  4 MiB
    unsigned short* H3h = (unsigned short*)alloc((size_t)Ss * BH * 2);  // 64 MiB
    unsigned short* H3l = (unsigned short*)alloc((size_t)Ss * BH * 2);  // 64 MiB
    float* cbuf = (float*)alloc(BH * 4);         // 8 MiB (sa c fp32; ta: lhA alias)
    float* lc   = (float*)alloc(BH * 4);         // 8 MiB
    unsigned short* lhBh = (unsigned short*)alloc(BH * 2);              // 4 MiB
    unsigned short* lhBl = (unsigned short*)alloc(BH * 2);              // 4 MiB
    unsigned short* xth = (unsigned short*)alloc((size_t)Bb * Dd * 2);  // 2 MiB
    unsigned short* xtl = (unsigned short*)alloc((size_t)Bb * Dd * 2);  // 2 MiB
    unsigned short* xsh = (unsigned short*)alloc((size_t)Bb * Dd * 2);  // 2 MiB
    unsigned short* xsl = (unsigned short*)alloc((size_t)Bb * Dd * 2);  // 2 MiB
    unsigned short* ch  = (unsigned short*)alloc(BH * 2);               // 4 MiB
    unsigned short* cl  = (unsigned short*)alloc(BH * 2);               // 4 MiB
    unsigned short* tmph = (unsigned short*)alloc((size_t)Bb * Dd * 2); // 2 MiB
    unsigned short* tmpl = (unsigned short*)alloc((size_t)Bb * Dd * 2); // 2 MiB
    unsigned short* saWth = (unsigned short*)alloc((size_t)Dd * 4 * Hh * 2);
    unsigned short* saWtl = (unsigned short*)alloc((size_t)Dd * 4 * Hh * 2);
    unsigned short* saUth = (unsigned short*)alloc((size_t)Hh * 4 * Hh * 2);
    unsigned short* saUtl = (unsigned short*)alloc((size_t)Hh * 4 * Hh * 2);
    unsigned short* taWth = (unsigned short*)alloc((size_t)Hh * 4 * Hh * 2);
    unsigned short* taWtl = (unsigned short*)alloc((size_t)Hh * 4 * Hh * 2);
    unsigned short* taUth = (unsigned short*)alloc((size_t)Hh * 4 * Hh * 2);
    unsigned short* taUtl = (unsigned short*)alloc((size_t)Hh * 4 * Hh * 2);
    unsigned short* WaTh = (unsigned short*)alloc((size_t)Dd * Dd * 2);
    unsigned short* WaTl = (unsigned short*)alloc((size_t)Dd * Dd * 2);
    unsigned short* UaTh = (unsigned short*)alloc((size_t)2 * Hh * Dd * 2);
    unsigned short* UaTl = (unsigned short*)alloc((size_t)2 * Hh * Dd * 2);
    unsigned short* VaTh = (unsigned short*)alloc((size_t)Dd * Dd * 2);
    unsigned short* VaTl = (unsigned short*)alloc((size_t)Dd * Dd * 2);
    unsigned short* tWaTh = (unsigned short*)alloc((size_t)16 * Hh * 2);
    unsigned short* tWaTl = (unsigned short*)alloc((size_t)16 * Hh * 2);
    float* yv = (float*)alloc((size_t)Bb * 4);
    // aliases (dead at time of reuse):
    float* beta = (float*)xth;                    // 4 MiB over xth+xtl (ta phase)
    unsigned short* lhAh = (unsigned short*)cbuf; // ta phase (cbuf dead)
    unsigned short* lhAl = (unsigned short*)cbuf + BH;
    unsigned short* lhh[2] = { lhAh, lhBh };
    unsigned short* lhl[2] = { lhAl, lhBl };
    // total ~188 MiB

    // ---- weight prep ----
    splitT_k<<<dim3(Dd / 32, (4 * Hh) / 32), 256, 0, stream>>>(sa_W, saWth, saWtl, Dd, 4 * Hh);
    splitT_k<<<dim3(Hh / 32, (4 * Hh) / 32), 256, 0, stream>>>(sa_U, saUth, saUtl, Hh, 4 * Hh);
    splitT_k<<<dim3(Hh / 32, (4 * Hh) / 32), 256, 0, stream>>>(ta_W, taWth, taWtl, Hh, 4 * Hh);
    splitT_k<<<dim3(Hh / 32, (4 * Hh) / 32), 256, 0, stream>>>(ta_U, taUth, taUtl, Hh, 4 * Hh);
    splitT_k<<<dim3(Dd / 32, Dd / 32), 256, 0, stream>>>(sa_Wa, WaTh, WaTl, Dd, Dd);
    splitT_k<<<dim3((2 * Hh) / 32, Dd / 32), 256, 0, stream>>>(sa_Ua, UaTh, UaTl, 2 * Hh, Dd);
    splitT_k<<<dim3(Dd / 32, Dd / 32), 256, 0, stream>>>(sa_Va, VaTh, VaTl, Dd, Dd);
    splitWa_k<<<dim3(32), 256, 0, stream>>>(ta_Wa, tWaTh, tWaTl);
    init_k<<<dim3((Bb * Dd) / 256), 256, 0, stream>>>(X, xsh, xsl, yv);

    const dim3 agrid(Bb / 32, Dd / 64);          // 128 x 4 = 512 blocks
    const dim3 ggrid(Bb / 128, Hh / 32);         // 32 x 16

    // ---- spatial-attention LSTM ----
    for (int t = 0; t < Ss; ++t) {
        // tmp = tanh(x_t @ sa_Wa + h @ Ua[:HS] + c @ Ua[HS:] + sa_ba) [MFMA]
        SegB a0{ xsh, xsl, WaTh, WaTl, Dd, Dd, Dd };
        if (t == 0) {
            gemm_mfma_k<32, 64, 1, 1><<<agrid, 256, 0, stream>>>(
                a0, a0, a0, sa_ba, nullptr, tmph, tmpl, Dd);
        } else {
            SegB a1{ H3h + (size_t)(t - 1) * BH, H3l + (size_t)(t - 1) * BH,
                     UaTh, UaTl, Hh, 2 * Hh, Hh };
            SegB a2{ ch, cl, UaTh + Hh, UaTl + Hh, Hh, 2 * Hh, Hh };
            gemm_mfma_k<32, 64, 3, 1><<<agrid, 256, 0, stream>>>(
                a0, a1, a2, sa_ba, nullptr, tmph, tmpl, Dd);
        }

        // av = tmp @ sa_Va  [MFMA]
        SegB v0{ tmph, tmpl, VaTh, VaTl, Dd, Dd, Dd };
        gemm_mfma_k<32, 64, 1, 0><<<agrid, 256, 0, stream>>>(
            v0, v0, v0, nullptr, avxt, nullptr, nullptr, Dd);

        if (t < Ss - 1)
            softmax_xt_k<1><<<Bb, 256, 0, stream>>>(avxt, X, xth, xtl, xsh, xsl, t);
        else
            softmax_xt_k<0><<<Bb, 256, 0, stream>>>(avxt, X, xth, xtl, xsh, xsl, t);

        // gates + LSTM fused
        SegB g0{ xth, xtl, saWth, saWtl, Dd, Dd, Dd };
        if (t == 0) {
            gemm_gates_k<1, 1, 0><<<ggrid, 256, 0, stream>>>(
                g0, g0, sa_b, nullptr, nullptr, cbuf,
                H3h + (size_t)t * BH, H3l + (size_t)t * BH, ch, cl);
        } else {
            SegB g1{ H3h + (size_t)(t - 1) * BH, H3l + (size_t)(t - 1) * BH,
                     saUth, saUtl, Hh, Hh, Hh };
            gemm_gates_k<2, 0, 0><<<ggrid, 256, 0, stream>>>(
                g0, g1, sa_b, nullptr, nullptr, cbuf,
                H3h + (size_t)t * BH, H3l + (size_t)t * BH, ch, cl);
        }
    }

    // ---- temporal attention: beta (MFMA+fused finish), then h_ctx in place ----
    beta_k<<<dim3((Ss * Bb) / 128), 256, 0, stream>>>(
        H3h, H3l, tWaTh, tWaTl, ta_ba, ta_Va, beta);
    hctx_all_k<<<Bb, 256, 0, stream>>>(H3h, H3l, beta);

    // ---- temporal LSTM (H3 planes now hold h_ctx); lh ping-pong ----
    for (int t = 0; t < Ss; ++t) {
        SegB g0{ H3h + (size_t)t * BH, H3l + (size_t)t * BH,
                 taWth, taWtl, Hh, Hh, Hh };
        const int po = t & 1;
        if (t == 0) {
            gemm_gates_k<1, 1, 1><<<ggrid, 256, 0, stream>>>(
                g0, g0, ta_b, ta_Wy, yv, lc, lhh[0], lhl[0], nullptr, nullptr);
        } else {
            SegB g1{ lhh[(t - 1) & 1], lhl[(t - 1) & 1], taUth, taUtl, Hh, Hh, Hh };
            gemm_gates_k<2, 0, 1><<<ggrid, 256, 0, stream>>>(
                g0, g1, ta_b, ta_Wy, yv, lc, lhh[po], lhl[po], nullptr, nullptr);
        }
        y_k<<<Bb, 256, 0, stream>>>(lhh[po], lhl[po], fc_W, fc_b, yv,
                                    (t == Ss - 1) ? (float*)d_out : nullptr);
    }
}